// Round 15
// baseline (450.183 us; speedup 1.0000x reference)
//
#include <hip/hip_runtime.h>
#include <hip/hip_bf16.h>

// ---------------------------------------------------------------------------
// GATv2 (2 conv + GraphNorm + MLP) on MI355X.
// Round 15: GEMM epilogue LDS halved (cs[128][72], 18KB) with 2-pass drain
// -> blocks/CU 2-4 -> 6, tripling in-flight bytes (r14 showed the GEMM is
// concurrency-limited at 922 GB/s). NORM fusion + everything else unchanged.
// ---------------------------------------------------------------------------

typedef __bf16 bf16x8 __attribute__((ext_vector_type(8)));
typedef float  f32x4  __attribute__((ext_vector_type(4)));

__device__ __forceinline__ unsigned short f2b(float f) {   // RNE f32->bf16
    unsigned u = __float_as_uint(f);
    return (unsigned short)((u + 0x7fffu + ((u >> 16) & 1u)) >> 16);
}

// norm+relu a packed bf16 pair (lo=ch2i, hi=ch2i+1), RNE repack in 1 instr
__device__ __forceinline__ unsigned pk_norm(unsigned u, float a0, float a1,
                                            float c0, float c1) {
    float lo = __uint_as_float(u << 16);
    float hi = __uint_as_float(u & 0xffff0000u);
    lo = fmaxf(fmaf(a0, lo, c0), 0.f);
    hi = fmaxf(fmaf(a1, hi, c1), 0.f);
    unsigned r;
    asm volatile("v_cvt_pk_bf16_f32 %0, %1, %2" : "=v"(r) : "v"(lo), "v"(hi));
    return r;
}

// ----------------------------- fused prep ----------------------------------
__global__ __launch_bounds__(256) void prep_all(
    const float* __restrict__ x, unsigned short* __restrict__ xbf, int nx4,
    const float* __restrict__ w0l, const float* __restrict__ w0r, unsigned short* __restrict__ Wt0,
    const float* __restrict__ w1l, const float* __restrict__ w1r, unsigned short* __restrict__ Wt1,
    const float* __restrict__ l0, unsigned short* __restrict__ Lt0,
    const float* __restrict__ l1, unsigned short* __restrict__ Lt1,
    float* __restrict__ zf, int* __restrict__ hist, int nh)
{
    int t = blockIdx.x * 256 + threadIdx.x;
    if (t < 512) { zf[t] = 0.f; }
    int i = t - 512;
    if (i >= 0 && i < nh) hist[i] = 0;
    i -= nh;
    if (i >= 0 && i < nx4) {
        float4 v = ((const float4*)x)[i];
        ushort4 o = { f2b(v.x), f2b(v.y), f2b(v.z), f2b(v.w) };
        ((ushort4*)xbf)[i] = o;
    }
    i -= nx4;
    if (i >= 0 && i < 32768) { int nn = i >> 7, kk = i & 127; Wt0[i] = f2b(w0l[kk * 256 + nn]); }
    i -= 32768;
    if (i >= 0 && i < 32768) { int nn = i >> 7, kk = i & 127; Wt0[32768 + i] = f2b(w0r[kk * 256 + nn]); }
    i -= 32768;
    if (i >= 0 && i < 65536) { int nn = i >> 8, kk = i & 255; Wt1[i] = f2b(w1l[kk * 256 + nn]); }
    i -= 65536;
    if (i >= 0 && i < 65536) { int nn = i >> 8, kk = i & 255; Wt1[65536 + i] = f2b(w1r[kk * 256 + nn]); }
    i -= 65536;
    if (i >= 0 && i < 16384) { int nn = i >> 8, kk = i & 255; Lt0[i] = f2b(l0[kk * 64 + nn]); }
    i -= 16384;
    if (i >= 0 && i < 4096)  { int nn = i >> 6, kk = i & 63;  Lt1[i] = f2b(l1[kk * 64 + nn]); }
}

// ----------------------------- MFMA GEMM -----------------------------------
// C[M,N](bf16) = act((norm(A))[M,K] @ Bt[N,K]^T + bias); K compile-time.
// Block: 4 waves, tile 256(M)x64(N); wave w owns rows [w*64, w*64+64).
// Epilogue: 18KB LDS (128 rows), 2-pass drain (waves 0-1 then 2-3) ->
// 6 blocks/CU instead of 2-4 (concurrency fix, r14 PMC).
template<int K, bool RELU, bool NORM>
__global__ __launch_bounds__(256) void mfma_gemm(
    const unsigned short* __restrict__ A, const unsigned short* __restrict__ Bt,
    const float* __restrict__ bias0, const float* __restrict__ bias1, int split,
    const float* __restrict__ na, const float* __restrict__ nc,
    unsigned short* __restrict__ C, int M, int N, int nt)
{
    __shared__ unsigned short cs[128][72];   // 18KB; row stride 144B

    // XCD-bijective swizzle of flat block id (m204 formula)
    const int nwg = gridDim.x;
    const int bid = blockIdx.x;
    const int q = nwg >> 3, r = nwg & 7;
    const int xcd = bid & 7, pos = bid >> 3;
    const int wgid = (xcd < r ? xcd * (q + 1) : r * (q + 1) + (xcd - r) * q) + pos;
    const int tm = wgid / nt;
    const int tn = wgid - tm * nt;

    const int lane = threadIdx.x & 63;
    const int w = threadIdx.x >> 6;
    const int bm = tm * 256 + w * 64;
    const int bn = tn * 64;
    const int lr = lane & 15;
    const int g  = lane >> 4;
    const int lk = g * 8;

    f32x4 acc[4][4] = {};
    const unsigned short* pa[4];
    #pragma unroll
    for (int mi = 0; mi < 4; ++mi) {
        int rr = bm + mi * 16 + lr;
        if (rr >= M) rr = M - 1;         // clamp (writes are guarded)
        pa[mi] = A + (size_t)rr * K + lk;
    }
    const unsigned short* pb = Bt + (size_t)(bn + lr) * K + lk;

    #pragma unroll
    for (int k0 = 0; k0 < K; k0 += 32) {
        bf16x8 bfr[4], afr[4];
        #pragma unroll
        for (int ni = 0; ni < 4; ++ni)
            bfr[ni] = *(const bf16x8*)(pb + (size_t)ni * 16 * K + k0);
        if constexpr (NORM) {
            const float4 av0 = *(const float4*)(na + k0 + lk);
            const float4 av1 = *(const float4*)(na + k0 + lk + 4);
            const float4 cv0 = *(const float4*)(nc + k0 + lk);
            const float4 cv1 = *(const float4*)(nc + k0 + lk + 4);
            #pragma unroll
            for (int mi = 0; mi < 4; ++mi) {
                uint4 u = *(const uint4*)(pa[mi] + k0);
                uint4 rr;
                rr.x = pk_norm(u.x, av0.x, av0.y, cv0.x, cv0.y);
                rr.y = pk_norm(u.y, av0.z, av0.w, cv0.z, cv0.w);
                rr.z = pk_norm(u.z, av1.x, av1.y, cv1.x, cv1.y);
                rr.w = pk_norm(u.w, av1.z, av1.w, cv1.z, cv1.w);
                afr[mi] = __builtin_bit_cast(bf16x8, rr);
            }
        } else {
            #pragma unroll
            for (int mi = 0; mi < 4; ++mi)
                afr[mi] = *(const bf16x8*)(pa[mi] + k0);
        }
        #pragma unroll
        for (int mi = 0; mi < 4; ++mi)
            #pragma unroll
            for (int ni = 0; ni < 4; ++ni)
                acc[mi][ni] = __builtin_amdgcn_mfma_f32_16x16x32_bf16(
                    bfr[ni], afr[mi], acc[mi][ni], 0, 0, 0);
    }

    // 2-pass epilogue: half h stages waves {2h, 2h+1} (tile rows h*128..+127)
    const int row32 = threadIdx.x >> 3;
    const int seg = threadIdx.x & 7;
    #pragma unroll
    for (int h = 0; h < 2; ++h) {
        if ((w >> 1) == h) {
            #pragma unroll
            for (int ni = 0; ni < 4; ++ni) {
                const int colbase = bn + ni * 16 + g * 4;
                const float4 bv = (colbase < split)
                    ? *(const float4*)(bias0 + colbase)
                    : *(const float4*)(bias1 + (colbase - split));
                #pragma unroll
                for (int mi = 0; mi < 4; ++mi) {
                    float v0 = acc[mi][ni][0] + bv.x;
                    float v1 = acc[mi][ni][1] + bv.y;
                    float v2 = acc[mi][ni][2] + bv.z;
                    float v3 = acc[mi][ni][3] + bv.w;
                    if (RELU) {
                        v0 = fmaxf(v0, 0.f); v1 = fmaxf(v1, 0.f);
                        v2 = fmaxf(v2, 0.f); v3 = fmaxf(v3, 0.f);
                    }
                    ushort4 o = { f2b(v0), f2b(v1), f2b(v2), f2b(v3) };
                    *(ushort4*)&cs[(w & 1) * 64 + mi * 16 + lr][ni * 16 + g * 4] = o;
                }
            }
        }
        __syncthreads();
        // all 256 threads drain 128 rows: 4 passes x (32 rows x 8 segs of 16B)
        #pragma unroll
        for (int p = 0; p < 4; ++p) {
            const int lrow = p * 32 + row32;
            const int grow = tm * 256 + h * 128 + lrow;
            if (grow < M)
                *(uint4*)(C + (size_t)grow * N + bn + seg * 8) =
                    *(const uint4*)&cs[lrow][seg * 8];
        }
        __syncthreads();
    }
}

// ----------------------------- CSR build (by dst) --------------------------
__global__ void hist_kernel(const int* __restrict__ dst, int E, int* __restrict__ hist) {
    int e = blockIdx.x * 256 + threadIdx.x;
    if (e < E) atomicAdd(&hist[dst[e]], 1);
}

__global__ void blk_sum_kernel(const int* __restrict__ hist, int n, int* __restrict__ bsum) {
    __shared__ int lds[256];
    int t = threadIdx.x;
    int i = blockIdx.x * 256 + t;
    lds[t] = (i < n) ? hist[i] : 0;
    __syncthreads();
    for (int off = 128; off > 0; off >>= 1) {
        if (t < off) lds[t] += lds[t + off];
        __syncthreads();
    }
    if (t == 0) bsum[blockIdx.x] = lds[0];
}
__global__ void bsum_scan_kernel(int* __restrict__ bsum, int nblk,
                                 int* __restrict__ row_ptr, int n) {
    __shared__ int lds[256];
    int t = threadIdx.x;
    int v = (t < nblk) ? bsum[t] : 0;
    lds[t] = v;
    __syncthreads();
    for (int off = 1; off < 256; off <<= 1) {
        int u = (t >= off) ? lds[t - off] : 0;
        __syncthreads();
        lds[t] += u;
        __syncthreads();
    }
    if (t < nblk) bsum[t] = lds[t] - v;
    if (t == 255) row_ptr[n] = lds[255];
}
__global__ void final_scan_kernel(const int* __restrict__ hist, const int* __restrict__ bsum,
                                  int n, int* __restrict__ row_ptr, int* __restrict__ cursor) {
    __shared__ int lds[256];
    int t = threadIdx.x;
    int i = blockIdx.x * 256 + t;
    int v = (i < n) ? hist[i] : 0;
    lds[t] = v;
    __syncthreads();
    for (int off = 1; off < 256; off <<= 1) {
        int u = (t >= off) ? lds[t - off] : 0;
        __syncthreads();
        lds[t] += u;
        __syncthreads();
    }
    if (i < n) {
        int ex = bsum[blockIdx.x] + lds[t] - v;
        row_ptr[i] = ex;
        cursor[i] = ex;
    }
}

__global__ void scatter_kernel(const int* __restrict__ src, const int* __restrict__ dst,
                               int E, int* cursor, int* __restrict__ esrc)
{
    int e = blockIdx.x * 256 + threadIdx.x;
    if (e < E) {
        int pos = atomicAdd(&cursor[dst[e]], 1);
        esrc[pos] = src[e];
    }
}

// --------------------- fused GATv2 softmax + aggregation -------------------
template<int CTRL>
__device__ __forceinline__ float dppadd(float v) {
    return v + __int_as_float(__builtin_amdgcn_update_dpp(
        0, __float_as_int(v), CTRL, 0xf, 0xf, true));
}
__device__ __forceinline__ float red8(float v) {
    v = dppadd<0xB1>(v);    // quad_perm xor 1
    v = dppadd<0x4E>(v);    // quad_perm xor 2
    v = dppadd<0x141>(v);   // row_half_mirror
    return v;
}
__device__ __forceinline__ f32x4 unpA(uint4 u) {   // even channels (exact)
    f32x4 r;
    r.x = __uint_as_float(u.x << 16); r.y = __uint_as_float(u.y << 16);
    r.z = __uint_as_float(u.z << 16); r.w = __uint_as_float(u.w << 16);
    return r;
}
__device__ __forceinline__ f32x4 unpB(uint4 u) {   // odd channels (exact)
    f32x4 r;
    r.x = __uint_as_float(u.x & 0xffff0000u); r.y = __uint_as_float(u.y & 0xffff0000u);
    r.z = __uint_as_float(u.z & 0xffff0000u); r.w = __uint_as_float(u.w & 0xffff0000u);
    return r;
}

__global__ __launch_bounds__(256) void gat_aggregate(
    const unsigned short* __restrict__ xlr, const float* __restrict__ att,
    const int* __restrict__ row_ptr, const int* __restrict__ esrc,
    const float* __restrict__ bias, unsigned short* __restrict__ out, int n)
{
    const int lane = threadIdx.x & 63;
    const int node = __builtin_amdgcn_readfirstlane(blockIdx.x * 4 + (threadIdx.x >> 6));
    if (node >= n) return;
    const int sub = lane & 31;
    const int half = lane >> 5;
    const int c8 = sub * 8;

    const float LOG2E = 1.4426950408889634f;
    const float4 a0 = *(const float4*)(att + c8);
    const float4 a1 = *(const float4*)(att + c8 + 4);
    f32x4 attA = { a0.x, a0.z, a1.x, a1.z };   // even channels
    f32x4 attB = { a0.y, a0.w, a1.y, a1.w };   // odd channels
    attA *= LOG2E; attB *= LOG2E;

    const uint4 xru = *(const uint4*)(xlr + (size_t)node * 512 + 256 + c8);
    const f32x4 xrA = unpA(xru), xrB = unpB(xru);

    float m = -1e30f, s = 0.f;
    f32x4 accA = {}, accB = {};

    const int start = row_ptr[node];
    const int cnt = row_ptr[node + 1] - start + 1;   // raw edges + self
    const int kmax = (cnt + 1) >> 1;

    int idx = half;                                   // virtual edge index
    int srcv = (idx == 0) ? node : ((idx < cnt) ? esrc[start + idx - 1] : node);
    uint4 nu = *(const uint4*)(xlr + (size_t)srcv * 512 + c8);

    for (int k = 0; k < kmax; ++k) {
        const f32x4 vA = unpA(nu), vB = unpB(nu);
        const float mask = (idx < cnt) ? 1.f : 0.f;
        const int idxn = idx + 2;
        const int srcn = (idxn < cnt) ? esrc[start + idxn - 1] : node;
        nu = *(const uint4*)(xlr + (size_t)srcn * 512 + c8);   // prefetch

        // score: e = sum_c att[c] * lrelu(xl[src][c] + xr[dst][c])
        const f32x4 zA = vA + xrA, zB = vB + xrB;
        const f32x4 tA = __builtin_elementwise_max(zA, zA * 0.2f);
        const f32x4 tB = __builtin_elementwise_max(zB, zB * 0.2f);
        f32x4 p = attA * tA;
        p = __builtin_elementwise_fma(attB, tB, p);
        const float e = red8((p.x + p.z) + (p.y + p.w));

        const float d = e - m;
        if (__builtin_expect(__any(d > 8.f), 0)) {
            const float mn = fmaxf(m, e);
            const float cs = __builtin_amdgcn_exp2f(m - mn);
            const float w  = __builtin_amdgcn_exp2f(e - mn) * mask;
            s = fmaf(s, cs, w);
            const f32x4 w4 = { w, w, w, w }, cv = { cs, cs, cs, cs };
            accA = __builtin_elementwise_fma(accA, cv, w4 * vA);
            accB = __builtin_elementwise_fma(accB, cv, w4 * vB);
            m = mn;
        } else {
            const float w = __builtin_amdgcn_exp2f(d) * mask;
            s += w;
            const f32x4 w4 = { w, w, w, w };
            accA = __builtin_elementwise_fma(w4, vA, accA);
            accB = __builtin_elementwise_fma(w4, vB, accB);
        }
        idx = idxn;
    }

    // merge the two half-wave states (scale-invariant representation)
    const float m_o = __shfl_xor(m, 32);
    const float s_o = __shfl_xor(s, 32);
    f32x4 accAo, accBo;
    accAo.x = __shfl_xor(accA.x, 32); accAo.y = __shfl_xor(accA.y, 32);
    accAo.z = __shfl_xor(accA.z, 32); accAo.w = __shfl_xor(accA.w, 32);
    accBo.x = __shfl_xor(accB.x, 32); accBo.y = __shfl_xor(accB.y, 32);
    accBo.z = __shfl_xor(accB.z, 32); accBo.w = __shfl_xor(accB.w, 32);
    const float mn = fmaxf(m, m_o);
    const float c0 = __builtin_amdgcn_exp2f(m - mn);
    const float c1 = __builtin_amdgcn_exp2f(m_o - mn);
    const float st = s * c0 + s_o * c1;
    const float inv = 1.f / (st + 1e-16f);

    if (half == 0) {
        const f32x4 oA = (accA * c0 + accAo * c1) * inv;
        const f32x4 oB = (accB * c0 + accBo * c1) * inv;
        const float4 b0 = *(const float4*)(bias + c8);
        const float4 b1 = *(const float4*)(bias + c8 + 4);
        uint4 o;
        o.x = (unsigned)f2b(oA.x + b0.x) | ((unsigned)f2b(oB.x + b0.y) << 16);
        o.y = (unsigned)f2b(oA.y + b0.z) | ((unsigned)f2b(oB.y + b0.w) << 16);
        o.z = (unsigned)f2b(oA.z + b1.x) | ((unsigned)f2b(oB.z + b1.y) << 16);
        o.w = (unsigned)f2b(oA.w + b1.z) | ((unsigned)f2b(oB.w + b1.w) << 16);
        *(uint4*)(out + (size_t)node * 256 + c8) = o;
    }
}

// ------------------------------- GraphNorm (bf16) --------------------------
__global__ __launch_bounds__(256) void colstats_bf16(
    const unsigned short* __restrict__ x, int n,
    float* __restrict__ sum, float* __restrict__ sumsq)
{
    const int c = threadIdx.x;
    float s = 0.f, q = 0.f;
    for (int r = blockIdx.x; r < n; r += gridDim.x) {
        float v = __uint_as_float(((unsigned)x[(size_t)r * 256 + c]) << 16);
        s += v;
        q = fmaf(v, v, q);
    }
    atomicAdd(&sum[c], s);
    atomicAdd(&sumsq[c], q);
}
// computes affine coefficients and self-zeroes the stat accumulators
__global__ void norm_finalize(float* __restrict__ sum, float* __restrict__ sumsq,
                              const float* __restrict__ w, const float* __restrict__ b,
                              const float* __restrict__ ms,
                              float* __restrict__ a, float* __restrict__ c2, float invn)
{
    int i = threadIdx.x;
    float mean = sum[i] * invn;
    float ex2 = sumsq[i] * invn;
    float m = ms[i];
    float var = ex2 - 2.f * m * mean * mean + m * m * mean * mean;
    float av = w[i] * rsqrtf(var + 1e-5f);
    a[i] = av;
    c2[i] = b[i] - av * m * mean;
    sum[i] = 0.f;
    sumsq[i] = 0.f;
}

// ---------------------------------- lin2 -----------------------------------
__global__ void lin2_kernel(const unsigned short* __restrict__ h, const float* __restrict__ w,
                            const float* __restrict__ b, float* __restrict__ out, int n)
{
    int i = blockIdx.x * 256 + threadIdx.x;
    if (i >= n) return;
    float a0 = b[0], a1 = b[1];
    const unsigned short* hr = h + (size_t)i * 64;
    #pragma unroll
    for (int k = 0; k < 64; ++k) {
        float v = __uint_as_float(((unsigned)hr[k]) << 16);
        a0 = fmaf(v, w[k * 2 + 0], a0);
        a1 = fmaf(v, w[k * 2 + 1], a1);
    }
    out[i * 2 + 0] = a0;
    out[i * 2 + 1] = a1;
}

// ---------------------------------------------------------------------------
extern "C" void kernel_launch(void* const* d_in, const int* in_sizes, int n_in,
                              void* d_out, int out_size, void* d_ws, size_t ws_size,
                              hipStream_t stream)
{
    const float* x      = (const float*)d_in[0];
    const int*   eidx   = (const int*)d_in[1];
    const float* c0_wl  = (const float*)d_in[2];
    const float* c0_bl  = (const float*)d_in[3];
    const float* c0_wr  = (const float*)d_in[4];
    const float* c0_br  = (const float*)d_in[5];
    const float* c0_att = (const float*)d_in[6];
    const float* c0_bias= (const float*)d_in[7];
    const float* c1_wl  = (const float*)d_in[8];
    const float* c1_bl  = (const float*)d_in[9];
    const float* c1_wr  = (const float*)d_in[10];
    const float* c1_br  = (const float*)d_in[11];
    const float* c1_att = (const float*)d_in[12];
    const float* c1_bias= (const float*)d_in[13];
    const float* gn0_w  = (const float*)d_in[14];
    const float* gn0_b  = (const float*)d_in[15];
    const float* gn0_ms = (const float*)d_in[16];
    const float* gn1_w  = (const float*)d_in[17];
    const float* gn1_b  = (const float*)d_in[18];
    const float* gn1_ms = (const float*)d_in[19];
    const float* lin0_w = (const float*)d_in[20];
    const float* lin0_b = (const float*)d_in[21];
    const float* lin1_w = (const float*)d_in[22];
    const float* lin1_b = (const float*)d_in[23];
    const float* lin2_w = (const float*)d_in[24];
    const float* lin2_b = (const float*)d_in[25];

    const int n = in_sizes[0] / 128;   // 50000
    const int E = in_sizes[1] / 2;     // 800000
    const int* src = eidx;
    const int* dst = eidx + E;

    char* wsp = (char*)d_ws;
    size_t off = 0;
    auto alloc = [&](size_t bytes) -> void* {
        void* p = wsp + off;
        off = (off + bytes + 255) & ~(size_t)255;
        return p;
    };
    unsigned short* xbf  = (unsigned short*)alloc((size_t)n * 128 * 2);  // x bf16
    unsigned short* xlr  = (unsigned short*)alloc((size_t)n * 512 * 2);  // [xl|xr] bf16
    unsigned short* hbB  = (unsigned short*)alloc((size_t)n * 256 * 2);  // conv out bf16 (raw)
    unsigned short* mbuf = (unsigned short*)alloc((size_t)n * 64 * 2);
    unsigned short* mbuf2= (unsigned short*)alloc((size_t)n * 64 * 2);
    unsigned short* Wt0  = (unsigned short*)alloc((size_t)512 * 128 * 2);
    unsigned short* Wt1  = (unsigned short*)alloc((size_t)512 * 256 * 2);
    unsigned short* Lt0  = (unsigned short*)alloc((size_t)64 * 256 * 2);
    unsigned short* Lt1  = (unsigned short*)alloc((size_t)64 * 64 * 2);
    int*   esrc    = (int*)alloc((size_t)E * 4);
    int*   row_ptr = (int*)alloc((size_t)(n + 1) * 4);
    int*   cursor  = (int*)alloc((size_t)n * 4);
    int*   hist    = (int*)alloc((size_t)n * 4);
    int*   bsum    = (int*)alloc((size_t)256 * 4);
    float* s_sum   = (float*)alloc(256 * 4);   // contiguous: s_sum, s_sq
    float* s_sq    = (float*)alloc(256 * 4);
    float* s_a     = (float*)alloc(256 * 4);
    float* s_c     = (float*)alloc(256 * 4);

    // ---- fused prep: zero(s_sum,s_sq,hist) + cast + 6 transposes ----
    const int nx4 = n * 128 / 4;                       // 1.6M
    const int prep_total = 512 + n + nx4 + 32768 * 2 + 65536 * 2 + 16384 + 4096;
    prep_all<<<(prep_total + 255) / 256, 256, 0, stream>>>(
        x, xbf, nx4, c0_wl, c0_wr, Wt0, c1_wl, c1_wr, Wt1,
        lin0_w, Lt0, lin1_w, Lt1, s_sum, hist, n);

    // ---- CSR by dst (parallel scan) ----
    const int nblk = (n + 255) / 256;   // 196 <= 256
    hist_kernel<<<(E + 255) / 256, 256, 0, stream>>>(dst, E, hist);
    blk_sum_kernel<<<nblk, 256, 0, stream>>>(hist, n, bsum);
    bsum_scan_kernel<<<1, 256, 0, stream>>>(bsum, nblk, row_ptr, n);
    final_scan_kernel<<<nblk, 256, 0, stream>>>(hist, bsum, n, row_ptr, cursor);
    scatter_kernel<<<(E + 255) / 256, 256, 0, stream>>>(src, dst, E, cursor, esrc);

    const int mt = (n + 255) / 256;     // 196 M-tiles (256 rows each)
    const int gagg = (n + 3) / 4;

    // ---- conv0: GEMM + aggregate + stats ----
    mfma_gemm<128, false, false><<<mt * 8, 256, 0, stream>>>(
        xbf, Wt0, c0_bl, c0_br, 256, nullptr, nullptr, xlr, n, 512, 8);
    gat_aggregate<<<gagg, 256, 0, stream>>>(xlr, c0_att, row_ptr, esrc, c0_bias, hbB, n);
    colstats_bf16<<<512, 256, 0, stream>>>(hbB, n, s_sum, s_sq);
    norm_finalize<<<1, 256, 0, stream>>>(s_sum, s_sq, gn0_w, gn0_b, gn0_ms, s_a, s_c, 1.f / n);

    // ---- conv1: GEMM (gn0 norm fused on A) + aggregate + stats ----
    mfma_gemm<256, false, true><<<mt * 8, 256, 0, stream>>>(
        hbB, Wt1, c1_bl, c1_br, 256, s_a, s_c, xlr, n, 512, 8);
    gat_aggregate<<<gagg, 256, 0, stream>>>(xlr, c1_att, row_ptr, esrc, c1_bias, hbB, n);
    colstats_bf16<<<512, 256, 0, stream>>>(hbB, n, s_sum, s_sq);
    norm_finalize<<<1, 256, 0, stream>>>(s_sum, s_sq, gn1_w, gn1_b, gn1_ms, s_a, s_c, 1.f / n);

    // ---- MLP: lin0 (gn1 norm fused on A) -> lin1 -> lin2 ----
    mfma_gemm<256, true, true><<<mt, 256, 0, stream>>>(
        hbB, Lt0, lin0_b, lin0_b, 64, s_a, s_c, mbuf, n, 64, 1);
    mfma_gemm<64, true, false><<<mt, 256, 0, stream>>>(
        mbuf, Lt1, lin1_b, lin1_b, 64, nullptr, nullptr, mbuf2, n, 64, 1);
    lin2_kernel<<<(n + 255) / 256, 256, 0, stream>>>(mbuf2, lin2_w, lin2_b, (float*)d_out, n);
}

// Round 16
// 386.848 us; speedup vs baseline: 1.1637x; 1.1637x over previous
//
#include <hip/hip_runtime.h>
#include <hip/hip_bf16.h>

// ---------------------------------------------------------------------------
// GATv2 (2 conv + GraphNorm + MLP) on MI355X.
// Round 16: conv GEMMs rebuilt in the m97 structure — global_load_lds (16B)
// stages A/B k-panels into LDS (XOR-swizzled via pre-swizzled global source),
// ds_read_b128 fragments, 128x128 tile, 2-barrier K-loop, LDS-reused
// full-sector epilogue. (r12-r15 showed the direct-load K-loop is
// latency-bound at ~70us regardless of write traffic.) MLP keeps the r14
// kernel. Aggregate / CSR / norm unchanged.
// ---------------------------------------------------------------------------

typedef __bf16 bf16x8 __attribute__((ext_vector_type(8)));
typedef float  f32x4  __attribute__((ext_vector_type(4)));

__device__ __forceinline__ unsigned short f2b(float f) {   // RNE f32->bf16
    unsigned u = __float_as_uint(f);
    return (unsigned short)((u + 0x7fffu + ((u >> 16) & 1u)) >> 16);
}

// norm+relu a packed bf16 pair, RNE repack in 1 instr
__device__ __forceinline__ unsigned pk_norm(unsigned u, float a0, float a1,
                                            float c0, float c1) {
    float lo = __uint_as_float(u << 16);
    float hi = __uint_as_float(u & 0xffff0000u);
    lo = fmaxf(fmaf(a0, lo, c0), 0.f);
    hi = fmaxf(fmaf(a1, hi, c1), 0.f);
    unsigned r;
    asm volatile("v_cvt_pk_bf16_f32 %0, %1, %2" : "=v"(r) : "v"(lo), "v"(hi));
    return r;
}

// async global->LDS, 16 bytes per lane (lds dest = uniform base + lane*16)
__device__ __forceinline__ void gload_lds16(const unsigned short* g, unsigned short* l) {
    __builtin_amdgcn_global_load_lds(
        (const __attribute__((address_space(1))) unsigned int*)g,
        (__attribute__((address_space(3))) unsigned int*)l, 16, 0, 0);
}

// ----------------------------- fused prep ----------------------------------
__global__ __launch_bounds__(256) void prep_all(
    const float* __restrict__ x, unsigned short* __restrict__ xbf, int nx4,
    const float* __restrict__ w0l, const float* __restrict__ w0r, unsigned short* __restrict__ Wt0,
    const float* __restrict__ w1l, const float* __restrict__ w1r, unsigned short* __restrict__ Wt1,
    const float* __restrict__ l0, unsigned short* __restrict__ Lt0,
    const float* __restrict__ l1, unsigned short* __restrict__ Lt1,
    float* __restrict__ zf, int* __restrict__ hist, int nh)
{
    int t = blockIdx.x * 256 + threadIdx.x;
    if (t < 512) { zf[t] = 0.f; }
    int i = t - 512;
    if (i >= 0 && i < nh) hist[i] = 0;
    i -= nh;
    if (i >= 0 && i < nx4) {
        float4 v = ((const float4*)x)[i];
        ushort4 o = { f2b(v.x), f2b(v.y), f2b(v.z), f2b(v.w) };
        ((ushort4*)xbf)[i] = o;
    }
    i -= nx4;
    if (i >= 0 && i < 32768) { int nn = i >> 7, kk = i & 127; Wt0[i] = f2b(w0l[kk * 256 + nn]); }
    i -= 32768;
    if (i >= 0 && i < 32768) { int nn = i >> 7, kk = i & 127; Wt0[32768 + i] = f2b(w0r[kk * 256 + nn]); }
    i -= 32768;
    if (i >= 0 && i < 65536) { int nn = i >> 8, kk = i & 255; Wt1[i] = f2b(w1l[kk * 256 + nn]); }
    i -= 65536;
    if (i >= 0 && i < 65536) { int nn = i >> 8, kk = i & 255; Wt1[65536 + i] = f2b(w1r[kk * 256 + nn]); }
    i -= 65536;
    if (i >= 0 && i < 16384) { int nn = i >> 8, kk = i & 255; Lt0[i] = f2b(l0[kk * 64 + nn]); }
    i -= 16384;
    if (i >= 0 && i < 4096)  { int nn = i >> 6, kk = i & 63;  Lt1[i] = f2b(l1[kk * 64 + nn]); }
}

// ------------------- conv GEMM (m97 structure, 128x128) --------------------
// C[M,512](bf16) = (norm(A))[M,K](bf16) @ Bt[512,K]^T(bf16) + bias.
// 4 waves (2x2), wave computes 64x64 (4x4 frags). Per k-step (BK=32):
// stage A/B panels via global_load_lds (pre-swizzled source: slot^=row&3),
// barrier, swizzled ds_read_b128 frags, 16 MFMA/wave, barrier.
// Epilogue reuses LDS for full-sector stores.
template<int K, bool NORM>
__global__ __launch_bounds__(256) void conv_gemm(
    const unsigned short* __restrict__ A, const unsigned short* __restrict__ Bt,
    const float* __restrict__ bias0, const float* __restrict__ bias1, int split,
    const float* __restrict__ na, const float* __restrict__ nc,
    unsigned short* __restrict__ C, int M, int N, int nt)
{
    __shared__ unsigned short smem[128 * 136];    // 34.8KB: stage(16KB) / epilogue
    unsigned short* sA = smem;                    // [128][32] bf16, 8KB
    unsigned short* sB = smem + 4096;             // [128][32] bf16, 8KB

    // XCD-bijective swizzle (m204), M-fast flat index
    const int nwg = gridDim.x;
    const int bid = blockIdx.x;
    const int q = nwg >> 3, r = nwg & 7;
    const int xcd = bid & 7, pos = bid >> 3;
    const int wgid = (xcd < r ? xcd * (q + 1) : r * (q + 1) + (xcd - r) * q) + pos;
    const int tm = wgid / nt;
    const int tn = wgid - tm * nt;

    const int lane = threadIdx.x & 63;
    const int w = threadIdx.x >> 6;
    const int wm = w >> 1, wn = w & 1;
    const int bm = tm * 128;
    const int bn = tn * 128;
    const int lr = lane & 15;
    const int g  = lane >> 4;

    // stage addressing (per wave: 2 instrs for A, 2 for B; 16 rows each)
    const int srow = lane >> 2;                       // row within 16-row chunk
    const int sk   = ((lane & 3) ^ (srow & 3)) << 3;  // pre-swizzled k-offset (elems)
    const int aslot = (g ^ (lr & 3)) << 3;            // ds_read slot (elems)

    f32x4 acc[4][4] = {};

    for (int k0 = 0; k0 < K; k0 += 32) {
        // ---- stage: wave w covers rows [w*32, w*32+32) of both panels ----
        #pragma unroll
        for (int j = 0; j < 2; ++j) {
            const int row = w * 32 + j * 16 + srow;
            int ga = bm + row; if (ga >= M) ga = M - 1;
            gload_lds16(A + (size_t)ga * K + k0 + sk, sA + (size_t)(w * 32 + j * 16) * 32);
            gload_lds16(Bt + (size_t)(bn + row) * K + k0 + sk, sB + (size_t)(w * 32 + j * 16) * 32);
        }
        __syncthreads();   // drains vmcnt (global_load_lds) for all waves

        // ---- fragments from LDS (swizzled read) ----
        bf16x8 afr[4], bfr[4];
        #pragma unroll
        for (int mi = 0; mi < 4; ++mi) {
            const int row = wm * 64 + mi * 16 + lr;
            afr[mi] = *(const bf16x8*)(sA + row * 32 + aslot);
        }
        #pragma unroll
        for (int ni = 0; ni < 4; ++ni) {
            const int row = wn * 64 + ni * 16 + lr;
            bfr[ni] = *(const bf16x8*)(sB + row * 32 + aslot);
        }
        if constexpr (NORM) {
            const int lk = g * 8;
            const float4 av0 = *(const float4*)(na + k0 + lk);
            const float4 av1 = *(const float4*)(na + k0 + lk + 4);
            const float4 cv0 = *(const float4*)(nc + k0 + lk);
            const float4 cv1 = *(const float4*)(nc + k0 + lk + 4);
            #pragma unroll
            for (int mi = 0; mi < 4; ++mi) {
                uint4 u = __builtin_bit_cast(uint4, afr[mi]);
                uint4 rr;
                rr.x = pk_norm(u.x, av0.x, av0.y, cv0.x, cv0.y);
                rr.y = pk_norm(u.y, av0.z, av0.w, cv0.z, cv0.w);
                rr.z = pk_norm(u.z, av1.x, av1.y, cv1.x, cv1.y);
                rr.w = pk_norm(u.w, av1.z, av1.w, cv1.z, cv1.w);
                afr[mi] = __builtin_bit_cast(bf16x8, rr);
            }
        }
        #pragma unroll
        for (int mi = 0; mi < 4; ++mi)
            #pragma unroll
            for (int ni = 0; ni < 4; ++ni)
                acc[mi][ni] = __builtin_amdgcn_mfma_f32_16x16x32_bf16(
                    bfr[ni], afr[mi], acc[mi][ni], 0, 0, 0);
        __syncthreads();   // all reads done before next stage overwrites
    }

    // ---- epilogue: stage C tile in LDS (reuse), then full-sector stores ----
    unsigned short (*cs)[136] = (unsigned short(*)[136])smem;
    #pragma unroll
    for (int ni = 0; ni < 4; ++ni) {
        const int lcol = wn * 64 + ni * 16 + g * 4;
        const int col = bn + lcol;
        const float4 bv = (col < split)
            ? *(const float4*)(bias0 + col)
            : *(const float4*)(bias1 + (col - split));
        #pragma unroll
        for (int mi = 0; mi < 4; ++mi) {
            const int lrow = wm * 64 + mi * 16 + lr;
            ushort4 o = { f2b(acc[mi][ni][0] + bv.x), f2b(acc[mi][ni][1] + bv.y),
                          f2b(acc[mi][ni][2] + bv.z), f2b(acc[mi][ni][3] + bv.w) };
            *(ushort4*)&cs[lrow][lcol] = o;
        }
    }
    __syncthreads();
    const int seg = threadIdx.x & 15;          // 16 segs x 8 ushorts = 128 cols
    const int rb  = threadIdx.x >> 4;          // 16 rows per pass
    #pragma unroll
    for (int p = 0; p < 8; ++p) {
        const int lrow = p * 16 + rb;
        const int grow = bm + lrow;
        if (grow < M)
            *(uint4*)(C + (size_t)grow * N + bn + seg * 8) =
                *(const uint4*)&cs[lrow][seg * 8];
    }
}

// ----------------------- MLP GEMM (r14 structure) ---------------------------
template<int K, bool RELU, bool NORM>
__global__ __launch_bounds__(256) void mfma_gemm(
    const unsigned short* __restrict__ A, const unsigned short* __restrict__ Bt,
    const float* __restrict__ bias0, const float* __restrict__ bias1, int split,
    const float* __restrict__ na, const float* __restrict__ nc,
    unsigned short* __restrict__ C, int M, int N, int nt)
{
    __shared__ unsigned short cs[256][72];

    const int nwg = gridDim.x;
    const int bid = blockIdx.x;
    const int q = nwg >> 3, r = nwg & 7;
    const int xcd = bid & 7, pos = bid >> 3;
    const int wgid = (xcd < r ? xcd * (q + 1) : r * (q + 1) + (xcd - r) * q) + pos;
    const int tm = wgid / nt;
    const int tn = wgid - tm * nt;

    const int lane = threadIdx.x & 63;
    const int w = threadIdx.x >> 6;
    const int bm = tm * 256 + w * 64;
    const int bn = tn * 64;
    const int lr = lane & 15;
    const int g  = lane >> 4;
    const int lk = g * 8;

    f32x4 acc[4][4] = {};
    const unsigned short* pa[4];
    #pragma unroll
    for (int mi = 0; mi < 4; ++mi) {
        int rr = bm + mi * 16 + lr;
        if (rr >= M) rr = M - 1;
        pa[mi] = A + (size_t)rr * K + lk;
    }
    const unsigned short* pb = Bt + (size_t)(bn + lr) * K + lk;

    #pragma unroll
    for (int k0 = 0; k0 < K; k0 += 32) {
        bf16x8 bfr[4], afr[4];
        #pragma unroll
        for (int ni = 0; ni < 4; ++ni)
            bfr[ni] = *(const bf16x8*)(pb + (size_t)ni * 16 * K + k0);
        if constexpr (NORM) {
            const float4 av0 = *(const float4*)(na + k0 + lk);
            const float4 av1 = *(const float4*)(na + k0 + lk + 4);
            const float4 cv0 = *(const float4*)(nc + k0 + lk);
            const float4 cv1 = *(const float4*)(nc + k0 + lk + 4);
            #pragma unroll
            for (int mi = 0; mi < 4; ++mi) {
                uint4 u = *(const uint4*)(pa[mi] + k0);
                uint4 rr;
                rr.x = pk_norm(u.x, av0.x, av0.y, cv0.x, cv0.y);
                rr.y = pk_norm(u.y, av0.z, av0.w, cv0.z, cv0.w);
                rr.z = pk_norm(u.z, av1.x, av1.y, cv1.x, cv1.y);
                rr.w = pk_norm(u.w, av1.z, av1.w, cv1.z, cv1.w);
                afr[mi] = __builtin_bit_cast(bf16x8, rr);
            }
        } else {
            #pragma unroll
            for (int mi = 0; mi < 4; ++mi)
                afr[mi] = *(const bf16x8*)(pa[mi] + k0);
        }
        #pragma unroll
        for (int mi = 0; mi < 4; ++mi)
            #pragma unroll
            for (int ni = 0; ni < 4; ++ni)
                acc[mi][ni] = __builtin_amdgcn_mfma_f32_16x16x32_bf16(
                    bfr[ni], afr[mi], acc[mi][ni], 0, 0, 0);
    }

    #pragma unroll
    for (int ni = 0; ni < 4; ++ni) {
        const int colbase = bn + ni * 16 + g * 4;
        const float4 bv = (colbase < split)
            ? *(const float4*)(bias0 + colbase)
            : *(const float4*)(bias1 + (colbase - split));
        #pragma unroll
        for (int mi = 0; mi < 4; ++mi) {
            float v0 = acc[mi][ni][0] + bv.x;
            float v1 = acc[mi][ni][1] + bv.y;
            float v2 = acc[mi][ni][2] + bv.z;
            float v3 = acc[mi][ni][3] + bv.w;
            if (RELU) {
                v0 = fmaxf(v0, 0.f); v1 = fmaxf(v1, 0.f);
                v2 = fmaxf(v2, 0.f); v3 = fmaxf(v3, 0.f);
            }
            ushort4 o = { f2b(v0), f2b(v1), f2b(v2), f2b(v3) };
            *(ushort4*)&cs[w * 64 + mi * 16 + lr][ni * 16 + g * 4] = o;
        }
    }
    __syncthreads();
    const int row32 = threadIdx.x >> 3;
    const int seg = threadIdx.x & 7;
    #pragma unroll
    for (int p = 0; p < 8; ++p) {
        const int lrow = p * 32 + row32;
        const int grow = tm * 256 + lrow;
        if (grow < M)
            *(uint4*)(C + (size_t)grow * N + bn + seg * 8) =
                *(const uint4*)&cs[lrow][seg * 8];
    }
}

// ----------------------------- CSR build (by dst) --------------------------
__global__ void hist_kernel(const int* __restrict__ dst, int E, int* __restrict__ hist) {
    int e = blockIdx.x * 256 + threadIdx.x;
    if (e < E) atomicAdd(&hist[dst[e]], 1);
}
__global__ void blk_sum_kernel(const int* __restrict__ hist, int n, int* __restrict__ bsum) {
    __shared__ int lds[256];
    int t = threadIdx.x;
    int i = blockIdx.x * 256 + t;
    lds[t] = (i < n) ? hist[i] : 0;
    __syncthreads();
    for (int off = 128; off > 0; off >>= 1) {
        if (t < off) lds[t] += lds[t + off];
        __syncthreads();
    }
    if (t == 0) bsum[blockIdx.x] = lds[0];
}
__global__ void bsum_scan_kernel(int* __restrict__ bsum, int nblk,
                                 int* __restrict__ row_ptr, int n) {
    __shared__ int lds[256];
    int t = threadIdx.x;
    int v = (t < nblk) ? bsum[t] : 0;
    lds[t] = v;
    __syncthreads();
    for (int off = 1; off < 256; off <<= 1) {
        int u = (t >= off) ? lds[t - off] : 0;
        __syncthreads();
        lds[t] += u;
        __syncthreads();
    }
    if (t < nblk) bsum[t] = lds[t] - v;
    if (t == 255) row_ptr[n] = lds[255];
}
__global__ void final_scan_kernel(const int* __restrict__ hist, const int* __restrict__ bsum,
                                  int n, int* __restrict__ row_ptr, int* __restrict__ cursor) {
    __shared__ int lds[256];
    int t = threadIdx.x;
    int i = blockIdx.x * 256 + t;
    int v = (i < n) ? hist[i] : 0;
    lds[t] = v;
    __syncthreads();
    for (int off = 1; off < 256; off <<= 1) {
        int u = (t >= off) ? lds[t - off] : 0;
        __syncthreads();
        lds[t] += u;
        __syncthreads();
    }
    if (i < n) {
        int ex = bsum[blockIdx.x] + lds[t] - v;
        row_ptr[i] = ex;
        cursor[i] = ex;
    }
}
__global__ void scatter_kernel(const int* __restrict__ src, const int* __restrict__ dst,
                               int E, int* cursor, int* __restrict__ esrc)
{
    int e = blockIdx.x * 256 + threadIdx.x;
    if (e < E) {
        int pos = atomicAdd(&cursor[dst[e]], 1);
        esrc[pos] = src[e];
    }
}

// --------------------- fused GATv2 softmax + aggregation -------------------
template<int CTRL>
__device__ __forceinline__ float dppadd(float v) {
    return v + __int_as_float(__builtin_amdgcn_update_dpp(
        0, __float_as_int(v), CTRL, 0xf, 0xf, true));
}
__device__ __forceinline__ float red8(float v) {
    v = dppadd<0xB1>(v);
    v = dppadd<0x4E>(v);
    v = dppadd<0x141>(v);
    return v;
}
__device__ __forceinline__ f32x4 unpA(uint4 u) {
    f32x4 r;
    r.x = __uint_as_float(u.x << 16); r.y = __uint_as_float(u.y << 16);
    r.z = __uint_as_float(u.z << 16); r.w = __uint_as_float(u.w << 16);
    return r;
}
__device__ __forceinline__ f32x4 unpB(uint4 u) {
    f32x4 r;
    r.x = __uint_as_float(u.x & 0xffff0000u); r.y = __uint_as_float(u.y & 0xffff0000u);
    r.z = __uint_as_float(u.z & 0xffff0000u); r.w = __uint_as_float(u.w & 0xffff0000u);
    return r;
}

__global__ __launch_bounds__(256) void gat_aggregate(
    const unsigned short* __restrict__ xlr, const float* __restrict__ att,
    const int* __restrict__ row_ptr, const int* __restrict__ esrc,
    const float* __restrict__ bias, unsigned short* __restrict__ out, int n)
{
    const int lane = threadIdx.x & 63;
    const int node = __builtin_amdgcn_readfirstlane(blockIdx.x * 4 + (threadIdx.x >> 6));
    if (node >= n) return;
    const int sub = lane & 31;
    const int half = lane >> 5;
    const int c8 = sub * 8;

    const float LOG2E = 1.4426950408889634f;
    const float4 a0 = *(const float4*)(att + c8);
    const float4 a1 = *(const float4*)(att + c8 + 4);
    f32x4 attA = { a0.x, a0.z, a1.x, a1.z };
    f32x4 attB = { a0.y, a0.w, a1.y, a1.w };
    attA *= LOG2E; attB *= LOG2E;

    const uint4 xru = *(const uint4*)(xlr + (size_t)node * 512 + 256 + c8);
    const f32x4 xrA = unpA(xru), xrB = unpB(xru);

    float m = -1e30f, s = 0.f;
    f32x4 accA = {}, accB = {};

    const int start = row_ptr[node];
    const int cnt = row_ptr[node + 1] - start + 1;
    const int kmax = (cnt + 1) >> 1;

    int idx = half;
    int srcv = (idx == 0) ? node : ((idx < cnt) ? esrc[start + idx - 1] : node);
    uint4 nu = *(const uint4*)(xlr + (size_t)srcv * 512 + c8);

    for (int k = 0; k < kmax; ++k) {
        const f32x4 vA = unpA(nu), vB = unpB(nu);
        const float mask = (idx < cnt) ? 1.f : 0.f;
        const int idxn = idx + 2;
        const int srcn = (idxn < cnt) ? esrc[start + idxn - 1] : node;
        nu = *(const uint4*)(xlr + (size_t)srcn * 512 + c8);

        const f32x4 zA = vA + xrA, zB = vB + xrB;
        const f32x4 tA = __builtin_elementwise_max(zA, zA * 0.2f);
        const f32x4 tB = __builtin_elementwise_max(zB, zB * 0.2f);
        f32x4 p = attA * tA;
        p = __builtin_elementwise_fma(attB, tB, p);
        const float e = red8((p.x + p.z) + (p.y + p.w));

        const float d = e - m;
        if (__builtin_expect(__any(d > 8.f), 0)) {
            const float mn = fmaxf(m, e);
            const float cs = __builtin_amdgcn_exp2f(m - mn);
            const float w  = __builtin_amdgcn_exp2f(e - mn) * mask;
            s = fmaf(s, cs, w);
            const f32x4 w4 = { w, w, w, w }, cv = { cs, cs, cs, cs };
            accA = __builtin_elementwise_fma(accA, cv, w4 * vA);
            accB = __builtin_elementwise_fma(accB, cv, w4 * vB);
            m = mn;
        } else {
            const float w = __builtin_amdgcn_exp2f(d) * mask;
            s += w;
            const f32x4 w4 = { w, w, w, w };
            accA = __builtin_elementwise_fma(w4, vA, accA);
            accB = __builtin_elementwise_fma(w4, vB, accB);
        }
        idx = idxn;
    }

    const float m_o = __shfl_xor(m, 32);
    const float s_o = __shfl_xor(s, 32);
    f32x4 accAo, accBo;
    accAo.x = __shfl_xor(accA.x, 32); accAo.y = __shfl_xor(accA.y, 32);
    accAo.z = __shfl_xor(accA.z, 32); accAo.w = __shfl_xor(accA.w, 32);
    accBo.x = __shfl_xor(accB.x, 32); accBo.y = __shfl_xor(accB.y, 32);
    accBo.z = __shfl_xor(accB.z, 32); accBo.w = __shfl_xor(accB.w, 32);
    const float mn = fmaxf(m, m_o);
    const float c0 = __builtin_amdgcn_exp2f(m - mn);
    const float c1 = __builtin_amdgcn_exp2f(m_o - mn);
    const float st = s * c0 + s_o * c1;
    const float inv = 1.f / (st + 1e-16f);

    if (half == 0) {
        const f32x4 oA = (accA * c0 + accAo * c1) * inv;
        const f32x4 oB = (accB * c0 + accBo * c1) * inv;
        const float4 b0 = *(const float4*)(bias + c8);
        const float4 b1 = *(const float4*)(bias + c8 + 4);
        uint4 o;
        o.x = (unsigned)f2b(oA.x + b0.x) | ((unsigned)f2b(oB.x + b0.y) << 16);
        o.y = (unsigned)f2b(oA.y + b0.z) | ((unsigned)f2b(oB.y + b0.w) << 16);
        o.z = (unsigned)f2b(oA.z + b1.x) | ((unsigned)f2b(oB.z + b1.y) << 16);
        o.w = (unsigned)f2b(oA.w + b1.z) | ((unsigned)f2b(oB.w + b1.w) << 16);
        *(uint4*)(out + (size_t)node * 256 + c8) = o;
    }
}

// ------------------------------- GraphNorm (bf16) --------------------------
__global__ __launch_bounds__(256) void colstats_bf16(
    const unsigned short* __restrict__ x, int n,
    float* __restrict__ sum, float* __restrict__ sumsq)
{
    const int c = threadIdx.x;
    float s = 0.f, q = 0.f;
    for (int r = blockIdx.x; r < n; r += gridDim.x) {
        float v = __uint_as_float(((unsigned)x[(size_t)r * 256 + c]) << 16);
        s += v;
        q = fmaf(v, v, q);
    }
    atomicAdd(&sum[c], s);
    atomicAdd(&sumsq[c], q);
}
__global__ void norm_finalize(float* __restrict__ sum, float* __restrict__ sumsq,
                              const float* __restrict__ w, const float* __restrict__ b,
                              const float* __restrict__ ms,
                              float* __restrict__ a, float* __restrict__ c2, float invn)
{
    int i = threadIdx.x;
    float mean = sum[i] * invn;
    float ex2 = sumsq[i] * invn;
    float m = ms[i];
    float var = ex2 - 2.f * m * mean * mean + m * m * mean * mean;
    float av = w[i] * rsqrtf(var + 1e-5f);
    a[i] = av;
    c2[i] = b[i] - av * m * mean;
    sum[i] = 0.f;
    sumsq[i] = 0.f;
}

// ---------------------------------- lin2 -----------------------------------
__global__ void lin2_kernel(const unsigned short* __restrict__ h, const float* __restrict__ w,
                            const float* __restrict__ b, float* __restrict__ out, int n)
{
    int i = blockIdx.x * 256 + threadIdx.x;
    if (i >= n) return;
    float a0 = b[0], a1 = b[1];
    const unsigned short* hr = h + (size_t)i * 64;
    #pragma unroll
    for (int k = 0; k < 64; ++k) {
        float v = __uint_as_float(((unsigned)hr[k]) << 16);
        a0 = fmaf(v, w[k * 2 + 0], a0);
        a1 = fmaf(v, w[k * 2 + 1], a1);
    }
    out[i * 2 + 0] = a0;
    out[i * 2 + 1] = a1;
}

// ---------------------------------------------------------------------------
extern "C" void kernel_launch(void* const* d_in, const int* in_sizes, int n_in,
                              void* d_out, int out_size, void* d_ws, size_t ws_size,
                              hipStream_t stream)
{
    const float* x      = (const float*)d_in[0];
    const int*   eidx   = (const int*)d_in[1];
    const float* c0_wl  = (const float*)d_in[2];
    const float* c0_bl  = (const float*)d_in[3];
    const float* c0_wr  = (const float*)d_in[4];
    const float* c0_br  = (const float*)d_in[5];
    const float* c0_att = (const float*)d_in[6];
    const float* c0_bias= (const float*)d_in[7];
    const float* c1_wl  = (const float*)d_in[8];
    const float* c1_bl  = (const float*)d_in[9];
    const float* c1_wr  = (const float*)d_in[10];
    const float* c1_br  = (const float*)d_in[11];
    const float* c1_att = (const float*)d_in[12];
    const float* c1_bias= (const float*)d_in[13];
    const float* gn0_w  = (const float*)d_in[14];
    const float* gn0_b  = (const float*)d_in[15];
    const float* gn0_ms = (const float*)d_in[16];
    const float* gn1_w  = (const float*)d_in[17];
    const float* gn1_b  = (const float*)d_in[18];
    const float* gn1_ms = (const float*)d_in[19];
    const float* lin0_w = (const float*)d_in[20];
    const float* lin0_b = (const float*)d_in[21];
    const float* lin1_w = (const float*)d_in[22];
    const float* lin1_b = (const float*)d_in[23];
    const float* lin2_w = (const float*)d_in[24];
    const float* lin2_b = (const float*)d_in[25];

    const int n = in_sizes[0] / 128;   // 50000
    const int E = in_sizes[1] / 2;     // 800000
    const int* src = eidx;
    const int* dst = eidx + E;

    char* wsp = (char*)d_ws;
    size_t off = 0;
    auto alloc = [&](size_t bytes) -> void* {
        void* p = wsp + off;
        off = (off + bytes + 255) & ~(size_t)255;
        return p;
    };
    unsigned short* xbf  = (unsigned short*)alloc((size_t)n * 128 * 2);
    unsigned short* xlr  = (unsigned short*)alloc((size_t)n * 512 * 2);
    unsigned short* hbB  = (unsigned short*)alloc((size_t)n * 256 * 2);
    unsigned short* mbuf = (unsigned short*)alloc((size_t)n * 64 * 2);
    unsigned short* mbuf2= (unsigned short*)alloc((size_t)n * 64 * 2);
    unsigned short* Wt0  = (unsigned short*)alloc((size_t)512 * 128 * 2);
    unsigned short* Wt1  = (unsigned short*)alloc((size_t)512 * 256 * 2);
    unsigned short* Lt0  = (unsigned short*)alloc((size_t)64 * 256 * 2);
    unsigned short* Lt1  = (unsigned short*)alloc((size_t)64 * 64 * 2);
    int*   esrc    = (int*)alloc((size_t)E * 4);
    int*   row_ptr = (int*)alloc((size_t)(n + 1) * 4);
    int*   cursor  = (int*)alloc((size_t)n * 4);
    int*   hist    = (int*)alloc((size_t)n * 4);
    int*   bsum    = (int*)alloc((size_t)256 * 4);
    float* s_sum   = (float*)alloc(256 * 4);
    float* s_sq    = (float*)alloc(256 * 4);
    float* s_a     = (float*)alloc(256 * 4);
    float* s_c     = (float*)alloc(256 * 4);

    // ---- fused prep ----
    const int nx4 = n * 128 / 4;
    const int prep_total = 512 + n + nx4 + 32768 * 2 + 65536 * 2 + 16384 + 4096;
    prep_all<<<(prep_total + 255) / 256, 256, 0, stream>>>(
        x, xbf, nx4, c0_wl, c0_wr, Wt0, c1_wl, c1_wr, Wt1,
        lin0_w, Lt0, lin1_w, Lt1, s_sum, hist, n);

    // ---- CSR by dst ----
    const int nblk = (n + 255) / 256;
    hist_kernel<<<(E + 255) / 256, 256, 0, stream>>>(dst, E, hist);
    blk_sum_kernel<<<nblk, 256, 0, stream>>>(hist, n, bsum);
    bsum_scan_kernel<<<1, 256, 0, stream>>>(bsum, nblk, row_ptr, n);
    final_scan_kernel<<<nblk, 256, 0, stream>>>(hist, bsum, n, row_ptr, cursor);
    scatter_kernel<<<(E + 255) / 256, 256, 0, stream>>>(src, dst, E, cursor, esrc);

    const int mtc = (n + 127) / 128;    // 391 conv M-tiles
    const int mt  = (n + 255) / 256;    // 196 MLP M-tiles
    const int gagg = (n + 3) / 4;

    // ---- conv0: staged GEMM + aggregate + stats ----
    conv_gemm<128, false><<<mtc * 4, 256, 0, stream>>>(
        xbf, Wt0, c0_bl, c0_br, 256, nullptr, nullptr, xlr, n, 512, 4);
    gat_aggregate<<<gagg, 256, 0, stream>>>(xlr, c0_att, row_ptr, esrc, c0_bias, hbB, n);
    colstats_bf16<<<512, 256, 0, stream>>>(hbB, n, s_sum, s_sq);
    norm_finalize<<<1, 256, 0, stream>>>(s_sum, s_sq, gn0_w, gn0_b, gn0_ms, s_a, s_c, 1.f / n);

    // ---- conv1: staged GEMM (gn0 fused) + aggregate + stats ----
    conv_gemm<256, true><<<mtc * 4, 256, 0, stream>>>(
        hbB, Wt1, c1_bl, c1_br, 256, s_a, s_c, xlr, n, 512, 4);
    gat_aggregate<<<gagg, 256, 0, stream>>>(xlr, c1_att, row_ptr, esrc, c1_bias, hbB, n);
    colstats_bf16<<<512, 256, 0, stream>>>(hbB, n, s_sum, s_sq);
    norm_finalize<<<1, 256, 0, stream>>>(s_sum, s_sq, gn1_w, gn1_b, gn1_ms, s_a, s_c, 1.f / n);

    // ---- MLP ----
    mfma_gemm<256, true, true><<<mt, 256, 0, stream>>>(
        hbB, Lt0, lin0_b, lin0_b, 64, s_a, s_c, mbuf, n, 64, 1);
    mfma_gemm<64, true, false><<<mt, 256, 0, stream>>>(
        mbuf, Lt1, lin1_b, lin1_b, 64, nullptr, nullptr, mbuf2, n, 64, 1);
    lin2_kernel<<<(n + 255) / 256, 256, 0, stream>>>(mbuf2, lin2_w, lin2_b, (float*)d_out, n);
}

// Round 17
// 384.936 us; speedup vs baseline: 1.1695x; 1.0050x over previous
//
#include <hip/hip_runtime.h>
#include <hip/hip_bf16.h>

// ---------------------------------------------------------------------------
// GATv2 (2 conv + GraphNorm + MLP) on MI355X.
// Round 17: mid-tier consolidation — (1) whole MLP (lin0+lin1+lin2) fused
// into one kernel via wave-local LDS round-trips; (2) bsum scan inlined into
// final_scan (one fewer launch); (3) colstats grid 1024. Aggregate and
// conv GEMM (both at their measured floors) unchanged from round 16.
// ---------------------------------------------------------------------------

typedef __bf16 bf16x8 __attribute__((ext_vector_type(8)));
typedef float  f32x4  __attribute__((ext_vector_type(4)));

__device__ __forceinline__ unsigned short f2b(float f) {   // RNE f32->bf16
    unsigned u = __float_as_uint(f);
    return (unsigned short)((u + 0x7fffu + ((u >> 16) & 1u)) >> 16);
}

// norm+relu a packed bf16 pair, RNE repack in 1 instr
__device__ __forceinline__ unsigned pk_norm(unsigned u, float a0, float a1,
                                            float c0, float c1) {
    float lo = __uint_as_float(u << 16);
    float hi = __uint_as_float(u & 0xffff0000u);
    lo = fmaxf(fmaf(a0, lo, c0), 0.f);
    hi = fmaxf(fmaf(a1, hi, c1), 0.f);
    unsigned r;
    asm volatile("v_cvt_pk_bf16_f32 %0, %1, %2" : "=v"(r) : "v"(lo), "v"(hi));
    return r;
}

// async global->LDS, 16 bytes per lane
__device__ __forceinline__ void gload_lds16(const unsigned short* g, unsigned short* l) {
    __builtin_amdgcn_global_load_lds(
        (const __attribute__((address_space(1))) unsigned int*)g,
        (__attribute__((address_space(3))) unsigned int*)l, 16, 0, 0);
}

// ----------------------------- fused prep ----------------------------------
__global__ __launch_bounds__(256) void prep_all(
    const float* __restrict__ x, unsigned short* __restrict__ xbf, int nx4,
    const float* __restrict__ w0l, const float* __restrict__ w0r, unsigned short* __restrict__ Wt0,
    const float* __restrict__ w1l, const float* __restrict__ w1r, unsigned short* __restrict__ Wt1,
    const float* __restrict__ l0, unsigned short* __restrict__ Lt0,
    const float* __restrict__ l1, unsigned short* __restrict__ Lt1,
    float* __restrict__ zf, int* __restrict__ hist, int nh)
{
    int t = blockIdx.x * 256 + threadIdx.x;
    if (t < 512) { zf[t] = 0.f; }
    int i = t - 512;
    if (i >= 0 && i < nh) hist[i] = 0;
    i -= nh;
    if (i >= 0 && i < nx4) {
        float4 v = ((const float4*)x)[i];
        ushort4 o = { f2b(v.x), f2b(v.y), f2b(v.z), f2b(v.w) };
        ((ushort4*)xbf)[i] = o;
    }
    i -= nx4;
    if (i >= 0 && i < 32768) { int nn = i >> 7, kk = i & 127; Wt0[i] = f2b(w0l[kk * 256 + nn]); }
    i -= 32768;
    if (i >= 0 && i < 32768) { int nn = i >> 7, kk = i & 127; Wt0[32768 + i] = f2b(w0r[kk * 256 + nn]); }
    i -= 32768;
    if (i >= 0 && i < 65536) { int nn = i >> 8, kk = i & 255; Wt1[i] = f2b(w1l[kk * 256 + nn]); }
    i -= 65536;
    if (i >= 0 && i < 65536) { int nn = i >> 8, kk = i & 255; Wt1[65536 + i] = f2b(w1r[kk * 256 + nn]); }
    i -= 65536;
    if (i >= 0 && i < 16384) { int nn = i >> 8, kk = i & 255; Lt0[i] = f2b(l0[kk * 64 + nn]); }
    i -= 16384;
    if (i >= 0 && i < 4096)  { int nn = i >> 6, kk = i & 63;  Lt1[i] = f2b(l1[kk * 64 + nn]); }
}

// ------------------- conv GEMM (m97 structure, 128x128) --------------------
template<int K, bool NORM>
__global__ __launch_bounds__(256) void conv_gemm(
    const unsigned short* __restrict__ A, const unsigned short* __restrict__ Bt,
    const float* __restrict__ bias0, const float* __restrict__ bias1, int split,
    const float* __restrict__ na, const float* __restrict__ nc,
    unsigned short* __restrict__ C, int M, int N, int nt)
{
    __shared__ unsigned short smem[128 * 136];    // stage(16KB) / epilogue
    unsigned short* sA = smem;
    unsigned short* sB = smem + 4096;

    const int nwg = gridDim.x;
    const int bid = blockIdx.x;
    const int q = nwg >> 3, r = nwg & 7;
    const int xcd = bid & 7, pos = bid >> 3;
    const int wgid = (xcd < r ? xcd * (q + 1) : r * (q + 1) + (xcd - r) * q) + pos;
    const int tm = wgid / nt;
    const int tn = wgid - tm * nt;

    const int lane = threadIdx.x & 63;
    const int w = threadIdx.x >> 6;
    const int wm = w >> 1, wn = w & 1;
    const int bm = tm * 128;
    const int bn = tn * 128;
    const int lr = lane & 15;
    const int g  = lane >> 4;

    const int srow = lane >> 2;
    const int sk   = ((lane & 3) ^ (srow & 3)) << 3;
    const int aslot = (g ^ (lr & 3)) << 3;

    f32x4 acc[4][4] = {};

    for (int k0 = 0; k0 < K; k0 += 32) {
        #pragma unroll
        for (int j = 0; j < 2; ++j) {
            const int row = w * 32 + j * 16 + srow;
            int ga = bm + row; if (ga >= M) ga = M - 1;
            gload_lds16(A + (size_t)ga * K + k0 + sk, sA + (size_t)(w * 32 + j * 16) * 32);
            gload_lds16(Bt + (size_t)(bn + row) * K + k0 + sk, sB + (size_t)(w * 32 + j * 16) * 32);
        }
        __syncthreads();

        bf16x8 afr[4], bfr[4];
        #pragma unroll
        for (int mi = 0; mi < 4; ++mi) {
            const int row = wm * 64 + mi * 16 + lr;
            afr[mi] = *(const bf16x8*)(sA + row * 32 + aslot);
        }
        #pragma unroll
        for (int ni = 0; ni < 4; ++ni) {
            const int row = wn * 64 + ni * 16 + lr;
            bfr[ni] = *(const bf16x8*)(sB + row * 32 + aslot);
        }
        if constexpr (NORM) {
            const int lk = g * 8;
            const float4 av0 = *(const float4*)(na + k0 + lk);
            const float4 av1 = *(const float4*)(na + k0 + lk + 4);
            const float4 cv0 = *(const float4*)(nc + k0 + lk);
            const float4 cv1 = *(const float4*)(nc + k0 + lk + 4);
            #pragma unroll
            for (int mi = 0; mi < 4; ++mi) {
                uint4 u = __builtin_bit_cast(uint4, afr[mi]);
                uint4 rr;
                rr.x = pk_norm(u.x, av0.x, av0.y, cv0.x, cv0.y);
                rr.y = pk_norm(u.y, av0.z, av0.w, cv0.z, cv0.w);
                rr.z = pk_norm(u.z, av1.x, av1.y, cv1.x, cv1.y);
                rr.w = pk_norm(u.w, av1.z, av1.w, cv1.z, cv1.w);
                afr[mi] = __builtin_bit_cast(bf16x8, rr);
            }
        }
        #pragma unroll
        for (int mi = 0; mi < 4; ++mi)
            #pragma unroll
            for (int ni = 0; ni < 4; ++ni)
                acc[mi][ni] = __builtin_amdgcn_mfma_f32_16x16x32_bf16(
                    bfr[ni], afr[mi], acc[mi][ni], 0, 0, 0);
        __syncthreads();
    }

    unsigned short (*cs)[136] = (unsigned short(*)[136])smem;
    #pragma unroll
    for (int ni = 0; ni < 4; ++ni) {
        const int lcol = wn * 64 + ni * 16 + g * 4;
        const int col = bn + lcol;
        const float4 bv = (col < split)
            ? *(const float4*)(bias0 + col)
            : *(const float4*)(bias1 + (col - split));
        #pragma unroll
        for (int mi = 0; mi < 4; ++mi) {
            const int lrow = wm * 64 + mi * 16 + lr;
            ushort4 o = { f2b(acc[mi][ni][0] + bv.x), f2b(acc[mi][ni][1] + bv.y),
                          f2b(acc[mi][ni][2] + bv.z), f2b(acc[mi][ni][3] + bv.w) };
            *(ushort4*)&cs[lrow][lcol] = o;
        }
    }
    __syncthreads();
    const int seg = threadIdx.x & 15;
    const int rb  = threadIdx.x >> 4;
    #pragma unroll
    for (int p = 0; p < 8; ++p) {
        const int lrow = p * 16 + rb;
        const int grow = bm + lrow;
        if (grow < M)
            *(uint4*)(C + (size_t)grow * N + bn + seg * 8) =
                *(const uint4*)&cs[lrow][seg * 8];
    }
}

// --------------------- fused MLP: lin0 -> lin1 -> lin2 ---------------------
// Block = 4 waves x 64 rows. Per wave: lin0 (K=256, gn1-norm fused on A,
// MFMA) -> relu -> wave-local LDS; lin1 (K=64, A-frags from LDS) -> relu ->
// LDS; lin2 as per-lane 64-dot. No barriers (wave-local LDS ordering).
__global__ __launch_bounds__(256) void mlp_fused(
    const unsigned short* __restrict__ A,      // hbB [M][256]
    const unsigned short* __restrict__ L0t,    // [64][256]
    const float* __restrict__ b0,
    const float* __restrict__ na, const float* __restrict__ nc,
    const unsigned short* __restrict__ L1t,    // [64][64]
    const float* __restrict__ b1,
    const float* __restrict__ w2,              // [64][2] fp32
    const float* __restrict__ b2,              // [2]
    float* __restrict__ out, int M)
{
    __shared__ unsigned short hbuf[4][64][72];   // 36KB, row stride 144B

    const int nwg = gridDim.x;
    const int bid = blockIdx.x;
    const int q = nwg >> 3, r = nwg & 7;
    const int xcd = bid & 7, pos = bid >> 3;
    const int tm = (xcd < r ? xcd * (q + 1) : r * (q + 1) + (xcd - r) * q) + pos;

    const int lane = threadIdx.x & 63;
    const int w = threadIdx.x >> 6;
    const int bm = tm * 256 + w * 64;
    const int lr = lane & 15;
    const int g  = lane >> 4;
    const int lk = g * 8;

    // ---- phase 1: h0 = relu(norm(A) @ L0t^T + b0), 64x64 per wave ----
    f32x4 acc[4][4] = {};
    const unsigned short* pa[4];
    #pragma unroll
    for (int mi = 0; mi < 4; ++mi) {
        int rr = bm + mi * 16 + lr;
        if (rr >= M) rr = M - 1;
        pa[mi] = A + (size_t)rr * 256 + lk;
    }
    #pragma unroll
    for (int k0 = 0; k0 < 256; k0 += 32) {
        bf16x8 bfr[4], afr[4];
        #pragma unroll
        for (int ni = 0; ni < 4; ++ni)
            bfr[ni] = *(const bf16x8*)(L0t + (size_t)(ni * 16 + lr) * 256 + k0 + lk);
        const float4 av0 = *(const float4*)(na + k0 + lk);
        const float4 av1 = *(const float4*)(na + k0 + lk + 4);
        const float4 cv0 = *(const float4*)(nc + k0 + lk);
        const float4 cv1 = *(const float4*)(nc + k0 + lk + 4);
        #pragma unroll
        for (int mi = 0; mi < 4; ++mi) {
            uint4 u = *(const uint4*)(pa[mi] + k0);
            uint4 rr;
            rr.x = pk_norm(u.x, av0.x, av0.y, cv0.x, cv0.y);
            rr.y = pk_norm(u.y, av0.z, av0.w, cv0.z, cv0.w);
            rr.z = pk_norm(u.z, av1.x, av1.y, cv1.x, cv1.y);
            rr.w = pk_norm(u.w, av1.z, av1.w, cv1.z, cv1.w);
            afr[mi] = __builtin_bit_cast(bf16x8, rr);
        }
        #pragma unroll
        for (int mi = 0; mi < 4; ++mi)
            #pragma unroll
            for (int ni = 0; ni < 4; ++ni)
                acc[mi][ni] = __builtin_amdgcn_mfma_f32_16x16x32_bf16(
                    bfr[ni], afr[mi], acc[mi][ni], 0, 0, 0);
    }
    #pragma unroll
    for (int ni = 0; ni < 4; ++ni) {
        const int col = ni * 16 + g * 4;
        const float4 bv = *(const float4*)(b0 + col);
        #pragma unroll
        for (int mi = 0; mi < 4; ++mi) {
            ushort4 o = { f2b(fmaxf(acc[mi][ni][0] + bv.x, 0.f)),
                          f2b(fmaxf(acc[mi][ni][1] + bv.y, 0.f)),
                          f2b(fmaxf(acc[mi][ni][2] + bv.z, 0.f)),
                          f2b(fmaxf(acc[mi][ni][3] + bv.w, 0.f)) };
            *(ushort4*)&hbuf[w][mi * 16 + lr][col] = o;
        }
    }

    // ---- phase 2: h1 = relu(h0 @ L1t^T + b1), K=64 (A from wave-local LDS) ----
    f32x4 acc2[4][4] = {};
    #pragma unroll
    for (int k0 = 0; k0 < 64; k0 += 32) {
        bf16x8 bfr[4], afr[4];
        #pragma unroll
        for (int ni = 0; ni < 4; ++ni)
            bfr[ni] = *(const bf16x8*)(L1t + (size_t)(ni * 16 + lr) * 64 + k0 + lk);
        #pragma unroll
        for (int mi = 0; mi < 4; ++mi)
            afr[mi] = *(const bf16x8*)&hbuf[w][mi * 16 + lr][k0 + lk];
        #pragma unroll
        for (int mi = 0; mi < 4; ++mi)
            #pragma unroll
            for (int ni = 0; ni < 4; ++ni)
                acc2[mi][ni] = __builtin_amdgcn_mfma_f32_16x16x32_bf16(
                    bfr[ni], afr[mi], acc2[mi][ni], 0, 0, 0);
    }
    #pragma unroll
    for (int ni = 0; ni < 4; ++ni) {
        const int col = ni * 16 + g * 4;
        const float4 bv = *(const float4*)(b1 + col);
        #pragma unroll
        for (int mi = 0; mi < 4; ++mi) {
            ushort4 o = { f2b(fmaxf(acc2[mi][ni][0] + bv.x, 0.f)),
                          f2b(fmaxf(acc2[mi][ni][1] + bv.y, 0.f)),
                          f2b(fmaxf(acc2[mi][ni][2] + bv.z, 0.f)),
                          f2b(fmaxf(acc2[mi][ni][3] + bv.w, 0.f)) };
            *(ushort4*)&hbuf[w][mi * 16 + lr][col] = o;
        }
    }

    // ---- phase 3: lin2 — lane owns its local row (64-dot -> 2 outputs) ----
    float o0 = b2[0], o1 = b2[1];
    #pragma unroll
    for (int kb = 0; kb < 8; ++kb) {
        bf16x8 hv = *(const bf16x8*)&hbuf[w][lane][kb * 8];
        uint4 u = __builtin_bit_cast(uint4, hv);
        const unsigned uu[4] = { u.x, u.y, u.z, u.w };
        #pragma unroll
        for (int j = 0; j < 4; ++j) {
            const int k = kb * 8 + j * 2;
            float lo = __uint_as_float(uu[j] << 16);
            float hi = __uint_as_float(uu[j] & 0xffff0000u);
            o0 = fmaf(lo, w2[k * 2 + 0], o0);
            o1 = fmaf(lo, w2[k * 2 + 1], o1);
            o0 = fmaf(hi, w2[k * 2 + 2], o0);
            o1 = fmaf(hi, w2[k * 2 + 3], o1);
        }
    }
    const int grow = bm + lane;
    if (grow < M) {
        out[grow * 2 + 0] = o0;
        out[grow * 2 + 1] = o1;
    }
}

// ----------------------------- CSR build (by dst) --------------------------
__global__ void hist_kernel(const int* __restrict__ dst, int E, int* __restrict__ hist) {
    int e = blockIdx.x * 256 + threadIdx.x;
    if (e < E) atomicAdd(&hist[dst[e]], 1);
}
__global__ void blk_sum_kernel(const int* __restrict__ hist, int n, int* __restrict__ bsum) {
    __shared__ int lds[256];
    int t = threadIdx.x;
    int i = blockIdx.x * 256 + t;
    lds[t] = (i < n) ? hist[i] : 0;
    __syncthreads();
    for (int off = 128; off > 0; off >>= 1) {
        if (t < off) lds[t] += lds[t + off];
        __syncthreads();
    }
    if (t == 0) bsum[blockIdx.x] = lds[0];
}
// final scan with inline (redundant per-block) scan of the block sums
__global__ void final_scan_kernel(const int* __restrict__ hist, const int* __restrict__ bsum,
                                  int nblk, int n, int* __restrict__ row_ptr,
                                  int* __restrict__ cursor) {
    __shared__ int lds[256];
    __shared__ int boff[256];
    int t = threadIdx.x;
    boff[t] = (t < nblk) ? bsum[t] : 0;
    int i = blockIdx.x * 256 + t;
    int v = (i < n) ? hist[i] : 0;
    lds[t] = v;
    __syncthreads();
    for (int off = 1; off < 256; off <<= 1) {
        int u  = (t >= off) ? lds[t - off] : 0;
        int u2 = (t >= off) ? boff[t - off] : 0;
        __syncthreads();
        lds[t] += u;
        boff[t] += u2;
        __syncthreads();
    }
    if (i < n) {
        int base = (blockIdx.x == 0) ? 0 : boff[blockIdx.x - 1];
        int ex = base + lds[t] - v;
        row_ptr[i] = ex;
        cursor[i] = ex;
    }
    if (blockIdx.x == 0 && t == 0) row_ptr[n] = boff[nblk - 1];
}
__global__ void scatter_kernel(const int* __restrict__ src, const int* __restrict__ dst,
                               int E, int* cursor, int* __restrict__ esrc)
{
    int e = blockIdx.x * 256 + threadIdx.x;
    if (e < E) {
        int pos = atomicAdd(&cursor[dst[e]], 1);
        esrc[pos] = src[e];
    }
}

// --------------------- fused GATv2 softmax + aggregation -------------------
template<int CTRL>
__device__ __forceinline__ float dppadd(float v) {
    return v + __int_as_float(__builtin_amdgcn_update_dpp(
        0, __float_as_int(v), CTRL, 0xf, 0xf, true));
}
__device__ __forceinline__ float red8(float v) {
    v = dppadd<0xB1>(v);
    v = dppadd<0x4E>(v);
    v = dppadd<0x141>(v);
    return v;
}
__device__ __forceinline__ f32x4 unpA(uint4 u) {
    f32x4 r;
    r.x = __uint_as_float(u.x << 16); r.y = __uint_as_float(u.y << 16);
    r.z = __uint_as_float(u.z << 16); r.w = __uint_as_float(u.w << 16);
    return r;
}
__device__ __forceinline__ f32x4 unpB(uint4 u) {
    f32x4 r;
    r.x = __uint_as_float(u.x & 0xffff0000u); r.y = __uint_as_float(u.y & 0xffff0000u);
    r.z = __uint_as_float(u.z & 0xffff0000u); r.w = __uint_as_float(u.w & 0xffff0000u);
    return r;
}

__global__ __launch_bounds__(256) void gat_aggregate(
    const unsigned short* __restrict__ xlr, const float* __restrict__ att,
    const int* __restrict__ row_ptr, const int* __restrict__ esrc,
    const float* __restrict__ bias, unsigned short* __restrict__ out, int n)
{
    const int lane = threadIdx.x & 63;
    const int node = __builtin_amdgcn_readfirstlane(blockIdx.x * 4 + (threadIdx.x >> 6));
    if (node >= n) return;
    const int sub = lane & 31;
    const int half = lane >> 5;
    const int c8 = sub * 8;

    const float LOG2E = 1.4426950408889634f;
    const float4 a0 = *(const float4*)(att + c8);
    const float4 a1 = *(const float4*)(att + c8 + 4);
    f32x4 attA = { a0.x, a0.z, a1.x, a1.z };
    f32x4 attB = { a0.y, a0.w, a1.y, a1.w };
    attA *= LOG2E; attB *= LOG2E;

    const uint4 xru = *(const uint4*)(xlr + (size_t)node * 512 + 256 + c8);
    const f32x4 xrA = unpA(xru), xrB = unpB(xru);

    float m = -1e30f, s = 0.f;
    f32x4 accA = {}, accB = {};

    const int start = row_ptr[node];
    const int cnt = row_ptr[node + 1] - start + 1;
    const int kmax = (cnt + 1) >> 1;

    int idx = half;
    int srcv = (idx == 0) ? node : ((idx < cnt) ? esrc[start + idx - 1] : node);
    uint4 nu = *(const uint4*)(xlr + (size_t)srcv * 512 + c8);

    for (int k = 0; k < kmax; ++k) {
        const f32x4 vA = unpA(nu), vB = unpB(nu);
        const float mask = (idx < cnt) ? 1.f : 0.f;
        const int idxn = idx + 2;
        const int srcn = (idxn < cnt) ? esrc[start + idxn - 1] : node;
        nu = *(const uint4*)(xlr + (size_t)srcn * 512 + c8);

        const f32x4 zA = vA + xrA, zB = vB + xrB;
        const f32x4 tA = __builtin_elementwise_max(zA, zA * 0.2f);
        const f32x4 tB = __builtin_elementwise_max(zB, zB * 0.2f);
        f32x4 p = attA * tA;
        p = __builtin_elementwise_fma(attB, tB, p);
        const float e = red8((p.x + p.z) + (p.y + p.w));

        const float d = e - m;
        if (__builtin_expect(__any(d > 8.f), 0)) {
            const float mn = fmaxf(m, e);
            const float cs = __builtin_amdgcn_exp2f(m - mn);
            const float w  = __builtin_amdgcn_exp2f(e - mn) * mask;
            s = fmaf(s, cs, w);
            const f32x4 w4 = { w, w, w, w }, cv = { cs, cs, cs, cs };
            accA = __builtin_elementwise_fma(accA, cv, w4 * vA);
            accB = __builtin_elementwise_fma(accB, cv, w4 * vB);
            m = mn;
        } else {
            const float w = __builtin_amdgcn_exp2f(d) * mask;
            s += w;
            const f32x4 w4 = { w, w, w, w };
            accA = __builtin_elementwise_fma(w4, vA, accA);
            accB = __builtin_elementwise_fma(w4, vB, accB);
        }
        idx = idxn;
    }

    const float m_o = __shfl_xor(m, 32);
    const float s_o = __shfl_xor(s, 32);
    f32x4 accAo, accBo;
    accAo.x = __shfl_xor(accA.x, 32); accAo.y = __shfl_xor(accA.y, 32);
    accAo.z = __shfl_xor(accA.z, 32); accAo.w = __shfl_xor(accA.w, 32);
    accBo.x = __shfl_xor(accB.x, 32); accBo.y = __shfl_xor(accB.y, 32);
    accBo.z = __shfl_xor(accB.z, 32); accBo.w = __shfl_xor(accB.w, 32);
    const float mn = fmaxf(m, m_o);
    const float c0 = __builtin_amdgcn_exp2f(m - mn);
    const float c1 = __builtin_amdgcn_exp2f(m_o - mn);
    const float st = s * c0 + s_o * c1;
    const float inv = 1.f / (st + 1e-16f);

    if (half == 0) {
        const f32x4 oA = (accA * c0 + accAo * c1) * inv;
        const f32x4 oB = (accB * c0 + accBo * c1) * inv;
        const float4 b0 = *(const float4*)(bias + c8);
        const float4 b1 = *(const float4*)(bias + c8 + 4);
        uint4 o;
        o.x = (unsigned)f2b(oA.x + b0.x) | ((unsigned)f2b(oB.x + b0.y) << 16);
        o.y = (unsigned)f2b(oA.y + b0.z) | ((unsigned)f2b(oB.y + b0.w) << 16);
        o.z = (unsigned)f2b(oA.z + b1.x) | ((unsigned)f2b(oB.z + b1.y) << 16);
        o.w = (unsigned)f2b(oA.w + b1.z) | ((unsigned)f2b(oB.w + b1.w) << 16);
        *(uint4*)(out + (size_t)node * 256 + c8) = o;
    }
}

// ------------------------------- GraphNorm (bf16) --------------------------
__global__ __launch_bounds__(256) void colstats_bf16(
    const unsigned short* __restrict__ x, int n,
    float* __restrict__ sum, float* __restrict__ sumsq)
{
    const int c = threadIdx.x;
    float s = 0.f, q = 0.f;
    for (int r = blockIdx.x; r < n; r += gridDim.x) {
        float v = __uint_as_float(((unsigned)x[(size_t)r * 256 + c]) << 16);
        s += v;
        q = fmaf(v, v, q);
    }
    atomicAdd(&sum[c], s);
    atomicAdd(&sumsq[c], q);
}
__global__ void norm_finalize(float* __restrict__ sum, float* __restrict__ sumsq,
                              const float* __restrict__ w, const float* __restrict__ b,
                              const float* __restrict__ ms,
                              float* __restrict__ a, float* __restrict__ c2, float invn)
{
    int i = threadIdx.x;
    float mean = sum[i] * invn;
    float ex2 = sumsq[i] * invn;
    float m = ms[i];
    float var = ex2 - 2.f * m * mean * mean + m * m * mean * mean;
    float av = w[i] * rsqrtf(var + 1e-5f);
    a[i] = av;
    c2[i] = b[i] - av * m * mean;
    sum[i] = 0.f;
    sumsq[i] = 0.f;
}

// ---------------------------------------------------------------------------
extern "C" void kernel_launch(void* const* d_in, const int* in_sizes, int n_in,
                              void* d_out, int out_size, void* d_ws, size_t ws_size,
                              hipStream_t stream)
{
    const float* x      = (const float*)d_in[0];
    const int*   eidx   = (const int*)d_in[1];
    const float* c0_wl  = (const float*)d_in[2];
    const float* c0_bl  = (const float*)d_in[3];
    const float* c0_wr  = (const float*)d_in[4];
    const float* c0_br  = (const float*)d_in[5];
    const float* c0_att = (const float*)d_in[6];
    const float* c0_bias= (const float*)d_in[7];
    const float* c1_wl  = (const float*)d_in[8];
    const float* c1_bl  = (const float*)d_in[9];
    const float* c1_wr  = (const float*)d_in[10];
    const float* c1_br  = (const float*)d_in[11];
    const float* c1_att = (const float*)d_in[12];
    const float* c1_bias= (const float*)d_in[13];
    const float* gn0_w  = (const float*)d_in[14];
    const float* gn0_b  = (const float*)d_in[15];
    const float* gn0_ms = (const float*)d_in[16];
    const float* gn1_w  = (const float*)d_in[17];
    const float* gn1_b  = (const float*)d_in[18];
    const float* gn1_ms = (const float*)d_in[19];
    const float* lin0_w = (const float*)d_in[20];
    const float* lin0_b = (const float*)d_in[21];
    const float* lin1_w = (const float*)d_in[22];
    const float* lin1_b = (const float*)d_in[23];
    const float* lin2_w = (const float*)d_in[24];
    const float* lin2_b = (const float*)d_in[25];

    const int n = in_sizes[0] / 128;   // 50000
    const int E = in_sizes[1] / 2;     // 800000
    const int* src = eidx;
    const int* dst = eidx + E;

    char* wsp = (char*)d_ws;
    size_t off = 0;
    auto alloc = [&](size_t bytes) -> void* {
        void* p = wsp + off;
        off = (off + bytes + 255) & ~(size_t)255;
        return p;
    };
    unsigned short* xbf  = (unsigned short*)alloc((size_t)n * 128 * 2);
    unsigned short* xlr  = (unsigned short*)alloc((size_t)n * 512 * 2);
    unsigned short* hbB  = (unsigned short*)alloc((size_t)n * 256 * 2);
    unsigned short* Wt0  = (unsigned short*)alloc((size_t)512 * 128 * 2);
    unsigned short* Wt1  = (unsigned short*)alloc((size_t)512 * 256 * 2);
    unsigned short* Lt0  = (unsigned short*)alloc((size_t)64 * 256 * 2);
    unsigned short* Lt1  = (unsigned short*)alloc((size_t)64 * 64 * 2);
    int*   esrc    = (int*)alloc((size_t)E * 4);
    int*   row_ptr = (int*)alloc((size_t)(n + 1) * 4);
    int*   cursor  = (int*)alloc((size_t)n * 4);
    int*   hist    = (int*)alloc((size_t)n * 4);
    int*   bsum    = (int*)alloc((size_t)256 * 4);
    float* s_sum   = (float*)alloc(256 * 4);
    float* s_sq    = (float*)alloc(256 * 4);
    float* s_a     = (float*)alloc(256 * 4);
    float* s_c     = (float*)alloc(256 * 4);

    // ---- fused prep ----
    const int nx4 = n * 128 / 4;
    const int prep_total = 512 + n + nx4 + 32768 * 2 + 65536 * 2 + 16384 + 4096;
    prep_all<<<(prep_total + 255) / 256, 256, 0, stream>>>(
        x, xbf, nx4, c0_wl, c0_wr, Wt0, c1_wl, c1_wr, Wt1,
        lin0_w, Lt0, lin1_w, Lt1, s_sum, hist, n);

    // ---- CSR by dst ----
    const int nblk = (n + 255) / 256;   // 196
    hist_kernel<<<(E + 255) / 256, 256, 0, stream>>>(dst, E, hist);
    blk_sum_kernel<<<nblk, 256, 0, stream>>>(hist, n, bsum);
    final_scan_kernel<<<nblk, 256, 0, stream>>>(hist, bsum, nblk, n, row_ptr, cursor);
    scatter_kernel<<<(E + 255) / 256, 256, 0, stream>>>(src, dst, E, cursor, esrc);

    const int mtc = (n + 127) / 128;    // 391 conv M-tiles
    const int mt  = (n + 255) / 256;    // 196 MLP M-tiles
    const int gagg = (n + 3) / 4;

    // ---- conv0 ----
    conv_gemm<128, false><<<mtc * 4, 256, 0, stream>>>(
        xbf, Wt0, c0_bl, c0_br, 256, nullptr, nullptr, xlr, n, 512, 4);
    gat_aggregate<<<gagg, 256, 0, stream>>>(xlr, c0_att, row_ptr, esrc, c0_bias, hbB, n);
    colstats_bf16<<<1024, 256, 0, stream>>>(hbB, n, s_sum, s_sq);
    norm_finalize<<<1, 256, 0, stream>>>(s_sum, s_sq, gn0_w, gn0_b, gn0_ms, s_a, s_c, 1.f / n);

    // ---- conv1 (gn0 fused) ----
    conv_gemm<256, true><<<mtc * 4, 256, 0, stream>>>(
        hbB, Wt1, c1_bl, c1_br, 256, s_a, s_c, xlr, n, 512, 4);
    gat_aggregate<<<gagg, 256, 0, stream>>>(xlr, c1_att, row_ptr, esrc, c1_bias, hbB, n);
    colstats_bf16<<<1024, 256, 0, stream>>>(hbB, n, s_sum, s_sq);
    norm_finalize<<<1, 256, 0, stream>>>(s_sum, s_sq, gn1_w, gn1_b, gn1_ms, s_a, s_c, 1.f / n);

    // ---- fused MLP (gn1 fused on lin0's A) ----
    mlp_fused<<<mt, 256, 0, stream>>>(
        hbB, Lt0, lin0_b, s_a, s_c, Lt1, lin1_b, lin2_w, lin2_b, (float*)d_out, n);
}

// Round 18
// 381.792 us; speedup vs baseline: 1.1791x; 1.0082x over previous
//
#include <hip/hip_runtime.h>
#include <hip/hip_bf16.h>

// ---------------------------------------------------------------------------
// GATv2 (2 conv + GraphNorm + MLP) on MI355X.
// Round 18: conv GEMM BK=64 staging (half the barriers per K) + 8-deep XOR
// swizzle (chunk ^= row&7, 2-way conflicts instead of 4-way). Fragments
// consumed in two 32-wide halves so VGPR stays flat. Everything else
// unchanged from round 17.
// ---------------------------------------------------------------------------

typedef __bf16 bf16x8 __attribute__((ext_vector_type(8)));
typedef float  f32x4  __attribute__((ext_vector_type(4)));

__device__ __forceinline__ unsigned short f2b(float f) {   // RNE f32->bf16
    unsigned u = __float_as_uint(f);
    return (unsigned short)((u + 0x7fffu + ((u >> 16) & 1u)) >> 16);
}

// norm+relu a packed bf16 pair, RNE repack in 1 instr
__device__ __forceinline__ unsigned pk_norm(unsigned u, float a0, float a1,
                                            float c0, float c1) {
    float lo = __uint_as_float(u << 16);
    float hi = __uint_as_float(u & 0xffff0000u);
    lo = fmaxf(fmaf(a0, lo, c0), 0.f);
    hi = fmaxf(fmaf(a1, hi, c1), 0.f);
    unsigned r;
    asm volatile("v_cvt_pk_bf16_f32 %0, %1, %2" : "=v"(r) : "v"(lo), "v"(hi));
    return r;
}

// async global->LDS, 16 bytes per lane (lds dest = uniform base + lane*16)
__device__ __forceinline__ void gload_lds16(const unsigned short* g, unsigned short* l) {
    __builtin_amdgcn_global_load_lds(
        (const __attribute__((address_space(1))) unsigned int*)g,
        (__attribute__((address_space(3))) unsigned int*)l, 16, 0, 0);
}

// ----------------------------- fused prep ----------------------------------
__global__ __launch_bounds__(256) void prep_all(
    const float* __restrict__ x, unsigned short* __restrict__ xbf, int nx4,
    const float* __restrict__ w0l, const float* __restrict__ w0r, unsigned short* __restrict__ Wt0,
    const float* __restrict__ w1l, const float* __restrict__ w1r, unsigned short* __restrict__ Wt1,
    const float* __restrict__ l0, unsigned short* __restrict__ Lt0,
    const float* __restrict__ l1, unsigned short* __restrict__ Lt1,
    float* __restrict__ zf, int* __restrict__ hist, int nh)
{
    int t = blockIdx.x * 256 + threadIdx.x;
    if (t < 512) { zf[t] = 0.f; }
    int i = t - 512;
    if (i >= 0 && i < nh) hist[i] = 0;
    i -= nh;
    if (i >= 0 && i < nx4) {
        float4 v = ((const float4*)x)[i];
        ushort4 o = { f2b(v.x), f2b(v.y), f2b(v.z), f2b(v.w) };
        ((ushort4*)xbf)[i] = o;
    }
    i -= nx4;
    if (i >= 0 && i < 32768) { int nn = i >> 7, kk = i & 127; Wt0[i] = f2b(w0l[kk * 256 + nn]); }
    i -= 32768;
    if (i >= 0 && i < 32768) { int nn = i >> 7, kk = i & 127; Wt0[32768 + i] = f2b(w0r[kk * 256 + nn]); }
    i -= 32768;
    if (i >= 0 && i < 65536) { int nn = i >> 8, kk = i & 255; Wt1[i] = f2b(w1l[kk * 256 + nn]); }
    i -= 65536;
    if (i >= 0 && i < 65536) { int nn = i >> 8, kk = i & 255; Wt1[65536 + i] = f2b(w1r[kk * 256 + nn]); }
    i -= 65536;
    if (i >= 0 && i < 16384) { int nn = i >> 8, kk = i & 255; Lt0[i] = f2b(l0[kk * 64 + nn]); }
    i -= 16384;
    if (i >= 0 && i < 4096)  { int nn = i >> 6, kk = i & 63;  Lt1[i] = f2b(l1[kk * 64 + nn]); }
}

// ------------------- conv GEMM (m97 structure, 128x128, BK=64) -------------
// C[M,512](bf16) = (norm(A))[M,K](bf16) @ Bt[512,K]^T(bf16) + bias.
// 4 waves (2x2). Per BK=64 step: stage A/B 128x64-elem panels via
// global_load_lds (pre-swizzled source: chunk ^= row&7), one barrier,
// two 32-wide MFMA halves from swizzled ds_read_b128, one barrier.
template<int K, bool NORM>
__global__ __launch_bounds__(256) void conv_gemm(
    const unsigned short* __restrict__ A, const unsigned short* __restrict__ Bt,
    const float* __restrict__ bias0, const float* __restrict__ bias1, int split,
    const float* __restrict__ na, const float* __restrict__ nc,
    unsigned short* __restrict__ C, int M, int N, int nt)
{
    __shared__ unsigned short smem[128 * 136];    // 34.8KB; stage uses 32KB
    unsigned short* sA = smem;                    // [128][64] bf16, 16KB
    unsigned short* sB = smem + 8192;             // [128][64] bf16, 16KB

    const int nwg = gridDim.x;
    const int bid = blockIdx.x;
    const int q = nwg >> 3, r = nwg & 7;
    const int xcd = bid & 7, pos = bid >> 3;
    const int wgid = (xcd < r ? xcd * (q + 1) : r * (q + 1) + (xcd - r) * q) + pos;
    const int tm = wgid / nt;
    const int tn = wgid - tm * nt;

    const int lane = threadIdx.x & 63;
    const int w = threadIdx.x >> 6;
    const int wm = w >> 1, wn = w & 1;
    const int bm = tm * 128;
    const int bn = tn * 128;
    const int lr = lane & 15;
    const int g  = lane >> 4;

    // stage addressing: lane covers row (base + lane>>3), 16B chunk (lane&7),
    // source chunk pre-swizzled by row&7 so linear LDS ends up swizzled.
    const int srow = lane >> 3;                       // 0..7
    const int sk   = ((lane & 7) ^ srow) << 3;        // element offset in row

    f32x4 acc[4][4] = {};

    for (int k0 = 0; k0 < K; k0 += 64) {
        // ---- stage: wave w covers rows [w*32, w*32+32) of both panels ----
        #pragma unroll
        for (int j = 0; j < 4; ++j) {
            const int rbase = w * 32 + j * 8;
            int ga = bm + rbase + srow; if (ga >= M) ga = M - 1;
            gload_lds16(A + (size_t)ga * K + k0 + sk, sA + (size_t)rbase * 64);
            gload_lds16(Bt + (size_t)(bn + rbase + srow) * K + k0 + sk,
                        sB + (size_t)rbase * 64);
        }
        __syncthreads();   // drains vmcnt for all waves

        // ---- two 32-wide halves ----
        #pragma unroll
        for (int half = 0; half < 2; ++half) {
            const int cbase = half * 4 + g;           // chunk index 0..7
            bf16x8 afr[4], bfr[4];
            #pragma unroll
            for (int mi = 0; mi < 4; ++mi) {
                const int row = wm * 64 + mi * 16 + lr;
                afr[mi] = *(const bf16x8*)(sA + row * 64 + ((cbase ^ (row & 7)) << 3));
            }
            #pragma unroll
            for (int ni = 0; ni < 4; ++ni) {
                const int row = wn * 64 + ni * 16 + lr;
                bfr[ni] = *(const bf16x8*)(sB + row * 64 + ((cbase ^ (row & 7)) << 3));
            }
            if constexpr (NORM) {
                const int lk = half * 32 + g * 8;
                const float4 av0 = *(const float4*)(na + k0 + lk);
                const float4 av1 = *(const float4*)(na + k0 + lk + 4);
                const float4 cv0 = *(const float4*)(nc + k0 + lk);
                const float4 cv1 = *(const float4*)(nc + k0 + lk + 4);
                #pragma unroll
                for (int mi = 0; mi < 4; ++mi) {
                    uint4 u = __builtin_bit_cast(uint4, afr[mi]);
                    uint4 rr;
                    rr.x = pk_norm(u.x, av0.x, av0.y, cv0.x, cv0.y);
                    rr.y = pk_norm(u.y, av0.z, av0.w, cv0.z, cv0.w);
                    rr.z = pk_norm(u.z, av1.x, av1.y, cv1.x, cv1.y);
                    rr.w = pk_norm(u.w, av1.z, av1.w, cv1.z, cv1.w);
                    afr[mi] = __builtin_bit_cast(bf16x8, rr);
                }
            }
            #pragma unroll
            for (int mi = 0; mi < 4; ++mi)
                #pragma unroll
                for (int ni = 0; ni < 4; ++ni)
                    acc[mi][ni] = __builtin_amdgcn_mfma_f32_16x16x32_bf16(
                        bfr[ni], afr[mi], acc[mi][ni], 0, 0, 0);
        }
        __syncthreads();   // all reads done before next stage overwrites
    }

    // ---- epilogue: stage C tile in LDS (reuse), full-sector stores ----
    unsigned short (*cs)[136] = (unsigned short(*)[136])smem;
    #pragma unroll
    for (int ni = 0; ni < 4; ++ni) {
        const int lcol = wn * 64 + ni * 16 + g * 4;
        const int col = bn + lcol;
        const float4 bv = (col < split)
            ? *(const float4*)(bias0 + col)
            : *(const float4*)(bias1 + (col - split));
        #pragma unroll
        for (int mi = 0; mi < 4; ++mi) {
            const int lrow = wm * 64 + mi * 16 + lr;
            ushort4 o = { f2b(acc[mi][ni][0] + bv.x), f2b(acc[mi][ni][1] + bv.y),
                          f2b(acc[mi][ni][2] + bv.z), f2b(acc[mi][ni][3] + bv.w) };
            *(ushort4*)&cs[lrow][lcol] = o;
        }
    }
    __syncthreads();
    const int seg = threadIdx.x & 15;
    const int rb  = threadIdx.x >> 4;
    #pragma unroll
    for (int p = 0; p < 8; ++p) {
        const int lrow = p * 16 + rb;
        const int grow = bm + lrow;
        if (grow < M)
            *(uint4*)(C + (size_t)grow * N + bn + seg * 8) =
                *(const uint4*)&cs[lrow][seg * 8];
    }
}

// --------------------- fused MLP: lin0 -> lin1 -> lin2 ---------------------
__global__ __launch_bounds__(256) void mlp_fused(
    const unsigned short* __restrict__ A,
    const unsigned short* __restrict__ L0t,
    const float* __restrict__ b0,
    const float* __restrict__ na, const float* __restrict__ nc,
    const unsigned short* __restrict__ L1t,
    const float* __restrict__ b1,
    const float* __restrict__ w2,
    const float* __restrict__ b2,
    float* __restrict__ out, int M)
{
    __shared__ unsigned short hbuf[4][64][72];

    const int nwg = gridDim.x;
    const int bid = blockIdx.x;
    const int q = nwg >> 3, r = nwg & 7;
    const int xcd = bid & 7, pos = bid >> 3;
    const int tm = (xcd < r ? xcd * (q + 1) : r * (q + 1) + (xcd - r) * q) + pos;

    const int lane = threadIdx.x & 63;
    const int w = threadIdx.x >> 6;
    const int bm = tm * 256 + w * 64;
    const int lr = lane & 15;
    const int g  = lane >> 4;
    const int lk = g * 8;

    f32x4 acc[4][4] = {};
    const unsigned short* pa[4];
    #pragma unroll
    for (int mi = 0; mi < 4; ++mi) {
        int rr = bm + mi * 16 + lr;
        if (rr >= M) rr = M - 1;
        pa[mi] = A + (size_t)rr * 256 + lk;
    }
    #pragma unroll
    for (int k0 = 0; k0 < 256; k0 += 32) {
        bf16x8 bfr[4], afr[4];
        #pragma unroll
        for (int ni = 0; ni < 4; ++ni)
            bfr[ni] = *(const bf16x8*)(L0t + (size_t)(ni * 16 + lr) * 256 + k0 + lk);
        const float4 av0 = *(const float4*)(na + k0 + lk);
        const float4 av1 = *(const float4*)(na + k0 + lk + 4);
        const float4 cv0 = *(const float4*)(nc + k0 + lk);
        const float4 cv1 = *(const float4*)(nc + k0 + lk + 4);
        #pragma unroll
        for (int mi = 0; mi < 4; ++mi) {
            uint4 u = *(const uint4*)(pa[mi] + k0);
            uint4 rr;
            rr.x = pk_norm(u.x, av0.x, av0.y, cv0.x, cv0.y);
            rr.y = pk_norm(u.y, av0.z, av0.w, cv0.z, cv0.w);
            rr.z = pk_norm(u.z, av1.x, av1.y, cv1.x, cv1.y);
            rr.w = pk_norm(u.w, av1.z, av1.w, cv1.z, cv1.w);
            afr[mi] = __builtin_bit_cast(bf16x8, rr);
        }
        #pragma unroll
        for (int mi = 0; mi < 4; ++mi)
            #pragma unroll
            for (int ni = 0; ni < 4; ++ni)
                acc[mi][ni] = __builtin_amdgcn_mfma_f32_16x16x32_bf16(
                    bfr[ni], afr[mi], acc[mi][ni], 0, 0, 0);
    }
    #pragma unroll
    for (int ni = 0; ni < 4; ++ni) {
        const int col = ni * 16 + g * 4;
        const float4 bv = *(const float4*)(b0 + col);
        #pragma unroll
        for (int mi = 0; mi < 4; ++mi) {
            ushort4 o = { f2b(fmaxf(acc[mi][ni][0] + bv.x, 0.f)),
                          f2b(fmaxf(acc[mi][ni][1] + bv.y, 0.f)),
                          f2b(fmaxf(acc[mi][ni][2] + bv.z, 0.f)),
                          f2b(fmaxf(acc[mi][ni][3] + bv.w, 0.f)) };
            *(ushort4*)&hbuf[w][mi * 16 + lr][col] = o;
        }
    }

    f32x4 acc2[4][4] = {};
    #pragma unroll
    for (int k0 = 0; k0 < 64; k0 += 32) {
        bf16x8 bfr[4], afr[4];
        #pragma unroll
        for (int ni = 0; ni < 4; ++ni)
            bfr[ni] = *(const bf16x8*)(L1t + (size_t)(ni * 16 + lr) * 64 + k0 + lk);
        #pragma unroll
        for (int mi = 0; mi < 4; ++mi)
            afr[mi] = *(const bf16x8*)&hbuf[w][mi * 16 + lr][k0 + lk];
        #pragma unroll
        for (int mi = 0; mi < 4; ++mi)
            #pragma unroll
            for (int ni = 0; ni < 4; ++ni)
                acc2[mi][ni] = __builtin_amdgcn_mfma_f32_16x16x32_bf16(
                    bfr[ni], afr[mi], acc2[mi][ni], 0, 0, 0);
    }
    #pragma unroll
    for (int ni = 0; ni < 4; ++ni) {
        const int col = ni * 16 + g * 4;
        const float4 bv = *(const float4*)(b1 + col);
        #pragma unroll
        for (int mi = 0; mi < 4; ++mi) {
            ushort4 o = { f2b(fmaxf(acc2[mi][ni][0] + bv.x, 0.f)),
                          f2b(fmaxf(acc2[mi][ni][1] + bv.y, 0.f)),
                          f2b(fmaxf(acc2[mi][ni][2] + bv.z, 0.f)),
                          f2b(fmaxf(acc2[mi][ni][3] + bv.w, 0.f)) };
            *(ushort4*)&hbuf[w][mi * 16 + lr][col] = o;
        }
    }

    float o0 = b2[0], o1 = b2[1];
    #pragma unroll
    for (int kb = 0; kb < 8; ++kb) {
        bf16x8 hv = *(const bf16x8*)&hbuf[w][lane][kb * 8];
        uint4 u = __builtin_bit_cast(uint4, hv);
        const unsigned uu[4] = { u.x, u.y, u.z, u.w };
        #pragma unroll
        for (int j = 0; j < 4; ++j) {
            const int k = kb * 8 + j * 2;
            float lo = __uint_as_float(uu[j] << 16);
            float hi = __uint_as_float(uu[j] & 0xffff0000u);
            o0 = fmaf(lo, w2[k * 2 + 0], o0);
            o1 = fmaf(lo, w2[k * 2 + 1], o1);
            o0 = fmaf(hi, w2[k * 2 + 2], o0);
            o1 = fmaf(hi, w2[k * 2 + 3], o1);
        }
    }
    const int grow = bm + lane;
    if (grow < M) {
        out[grow * 2 + 0] = o0;
        out[grow * 2 + 1] = o1;
    }
}

// ----------------------------- CSR build (by dst) --------------------------
__global__ void hist_kernel(const int* __restrict__ dst, int E, int* __restrict__ hist) {
    int e = blockIdx.x * 256 + threadIdx.x;
    if (e < E) atomicAdd(&hist[dst[e]], 1);
}
__global__ void blk_sum_kernel(const int* __restrict__ hist, int n, int* __restrict__ bsum) {
    __shared__ int lds[256];
    int t = threadIdx.x;
    int i = blockIdx.x * 256 + t;
    lds[t] = (i < n) ? hist[i] : 0;
    __syncthreads();
    for (int off = 128; off > 0; off >>= 1) {
        if (t < off) lds[t] += lds[t + off];
        __syncthreads();
    }
    if (t == 0) bsum[blockIdx.x] = lds[0];
}
__global__ void final_scan_kernel(const int* __restrict__ hist, const int* __restrict__ bsum,
                                  int nblk, int n, int* __restrict__ row_ptr,
                                  int* __restrict__ cursor) {
    __shared__ int lds[256];
    __shared__ int boff[256];
    int t = threadIdx.x;
    boff[t] = (t < nblk) ? bsum[t] : 0;
    int i = blockIdx.x * 256 + t;
    int v = (i < n) ? hist[i] : 0;
    lds[t] = v;
    __syncthreads();
    for (int off = 1; off < 256; off <<= 1) {
        int u  = (t >= off) ? lds[t - off] : 0;
        int u2 = (t >= off) ? boff[t - off] : 0;
        __syncthreads();
        lds[t] += u;
        boff[t] += u2;
        __syncthreads();
    }
    if (i < n) {
        int base = (blockIdx.x == 0) ? 0 : boff[blockIdx.x - 1];
        int ex = base + lds[t] - v;
        row_ptr[i] = ex;
        cursor[i] = ex;
    }
    if (blockIdx.x == 0 && t == 0) row_ptr[n] = boff[nblk - 1];
}
__global__ void scatter_kernel(const int* __restrict__ src, const int* __restrict__ dst,
                               int E, int* cursor, int* __restrict__ esrc)
{
    int e = blockIdx.x * 256 + threadIdx.x;
    if (e < E) {
        int pos = atomicAdd(&cursor[dst[e]], 1);
        esrc[pos] = src[e];
    }
}

// --------------------- fused GATv2 softmax + aggregation -------------------
template<int CTRL>
__device__ __forceinline__ float dppadd(float v) {
    return v + __int_as_float(__builtin_amdgcn_update_dpp(
        0, __float_as_int(v), CTRL, 0xf, 0xf, true));
}
__device__ __forceinline__ float red8(float v) {
    v = dppadd<0xB1>(v);
    v = dppadd<0x4E>(v);
    v = dppadd<0x141>(v);
    return v;
}
__device__ __forceinline__ f32x4 unpA(uint4 u) {
    f32x4 r;
    r.x = __uint_as_float(u.x << 16); r.y = __uint_as_float(u.y << 16);
    r.z = __uint_as_float(u.z << 16); r.w = __uint_as_float(u.w << 16);
    return r;
}
__device__ __forceinline__ f32x4 unpB(uint4 u) {
    f32x4 r;
    r.x = __uint_as_float(u.x & 0xffff0000u); r.y = __uint_as_float(u.y & 0xffff0000u);
    r.z = __uint_as_float(u.z & 0xffff0000u); r.w = __uint_as_float(u.w & 0xffff0000u);
    return r;
}

__global__ __launch_bounds__(256) void gat_aggregate(
    const unsigned short* __restrict__ xlr, const float* __restrict__ att,
    const int* __restrict__ row_ptr, const int* __restrict__ esrc,
    const float* __restrict__ bias, unsigned short* __restrict__ out, int n)
{
    const int lane = threadIdx.x & 63;
    const int node = __builtin_amdgcn_readfirstlane(blockIdx.x * 4 + (threadIdx.x >> 6));
    if (node >= n) return;
    const int sub = lane & 31;
    const int half = lane >> 5;
    const int c8 = sub * 8;

    const float LOG2E = 1.4426950408889634f;
    const float4 a0 = *(const float4*)(att + c8);
    const float4 a1 = *(const float4*)(att + c8 + 4);
    f32x4 attA = { a0.x, a0.z, a1.x, a1.z };
    f32x4 attB = { a0.y, a0.w, a1.y, a1.w };
    attA *= LOG2E; attB *= LOG2E;

    const uint4 xru = *(const uint4*)(xlr + (size_t)node * 512 + 256 + c8);
    const f32x4 xrA = unpA(xru), xrB = unpB(xru);

    float m = -1e30f, s = 0.f;
    f32x4 accA = {}, accB = {};

    const int start = row_ptr[node];
    const int cnt = row_ptr[node + 1] - start + 1;
    const int kmax = (cnt + 1) >> 1;

    int idx = half;
    int srcv = (idx == 0) ? node : ((idx < cnt) ? esrc[start + idx - 1] : node);
    uint4 nu = *(const uint4*)(xlr + (size_t)srcv * 512 + c8);

    for (int k = 0; k < kmax; ++k) {
        const f32x4 vA = unpA(nu), vB = unpB(nu);
        const float mask = (idx < cnt) ? 1.f : 0.f;
        const int idxn = idx + 2;
        const int srcn = (idxn < cnt) ? esrc[start + idxn - 1] : node;
        nu = *(const uint4*)(xlr + (size_t)srcn * 512 + c8);

        const f32x4 zA = vA + xrA, zB = vB + xrB;
        const f32x4 tA = __builtin_elementwise_max(zA, zA * 0.2f);
        const f32x4 tB = __builtin_elementwise_max(zB, zB * 0.2f);
        f32x4 p = attA * tA;
        p = __builtin_elementwise_fma(attB, tB, p);
        const float e = red8((p.x + p.z) + (p.y + p.w));

        const float d = e - m;
        if (__builtin_expect(__any(d > 8.f), 0)) {
            const float mn = fmaxf(m, e);
            const float cs = __builtin_amdgcn_exp2f(m - mn);
            const float w  = __builtin_amdgcn_exp2f(e - mn) * mask;
            s = fmaf(s, cs, w);
            const f32x4 w4 = { w, w, w, w }, cv = { cs, cs, cs, cs };
            accA = __builtin_elementwise_fma(accA, cv, w4 * vA);
            accB = __builtin_elementwise_fma(accB, cv, w4 * vB);
            m = mn;
        } else {
            const float w = __builtin_amdgcn_exp2f(d) * mask;
            s += w;
            const f32x4 w4 = { w, w, w, w };
            accA = __builtin_elementwise_fma(w4, vA, accA);
            accB = __builtin_elementwise_fma(w4, vB, accB);
        }
        idx = idxn;
    }

    const float m_o = __shfl_xor(m, 32);
    const float s_o = __shfl_xor(s, 32);
    f32x4 accAo, accBo;
    accAo.x = __shfl_xor(accA.x, 32); accAo.y = __shfl_xor(accA.y, 32);
    accAo.z = __shfl_xor(accA.z, 32); accAo.w = __shfl_xor(accA.w, 32);
    accBo.x = __shfl_xor(accB.x, 32); accBo.y = __shfl_xor(accB.y, 32);
    accBo.z = __shfl_xor(accB.z, 32); accBo.w = __shfl_xor(accB.w, 32);
    const float mn = fmaxf(m, m_o);
    const float c0 = __builtin_amdgcn_exp2f(m - mn);
    const float c1 = __builtin_amdgcn_exp2f(m_o - mn);
    const float st = s * c0 + s_o * c1;
    const float inv = 1.f / (st + 1e-16f);

    if (half == 0) {
        const f32x4 oA = (accA * c0 + accAo * c1) * inv;
        const f32x4 oB = (accB * c0 + accBo * c1) * inv;
        const float4 b0 = *(const float4*)(bias + c8);
        const float4 b1 = *(const float4*)(bias + c8 + 4);
        uint4 o;
        o.x = (unsigned)f2b(oA.x + b0.x) | ((unsigned)f2b(oB.x + b0.y) << 16);
        o.y = (unsigned)f2b(oA.y + b0.z) | ((unsigned)f2b(oB.y + b0.w) << 16);
        o.z = (unsigned)f2b(oA.z + b1.x) | ((unsigned)f2b(oB.z + b1.y) << 16);
        o.w = (unsigned)f2b(oA.w + b1.z) | ((unsigned)f2b(oB.w + b1.w) << 16);
        *(uint4*)(out + (size_t)node * 256 + c8) = o;
    }
}

// ------------------------------- GraphNorm (bf16) --------------------------
__global__ __launch_bounds__(256) void colstats_bf16(
    const unsigned short* __restrict__ x, int n,
    float* __restrict__ sum, float* __restrict__ sumsq)
{
    const int c = threadIdx.x;
    float s = 0.f, q = 0.f;
    for (int r = blockIdx.x; r < n; r += gridDim.x) {
        float v = __uint_as_float(((unsigned)x[(size_t)r * 256 + c]) << 16);
        s += v;
        q = fmaf(v, v, q);
    }
    atomicAdd(&sum[c], s);
    atomicAdd(&sumsq[c], q);
}
__global__ void norm_finalize(float* __restrict__ sum, float* __restrict__ sumsq,
                              const float* __restrict__ w, const float* __restrict__ b,
                              const float* __restrict__ ms,
                              float* __restrict__ a, float* __restrict__ c2, float invn)
{
    int i = threadIdx.x;
    float mean = sum[i] * invn;
    float ex2 = sumsq[i] * invn;
    float m = ms[i];
    float var = ex2 - 2.f * m * mean * mean + m * m * mean * mean;
    float av = w[i] * rsqrtf(var + 1e-5f);
    a[i] = av;
    c2[i] = b[i] - av * m * mean;
    sum[i] = 0.f;
    sumsq[i] = 0.f;
}

// ---------------------------------------------------------------------------
extern "C" void kernel_launch(void* const* d_in, const int* in_sizes, int n_in,
                              void* d_out, int out_size, void* d_ws, size_t ws_size,
                              hipStream_t stream)
{
    const float* x      = (const float*)d_in[0];
    const int*   eidx   = (const int*)d_in[1];
    const float* c0_wl  = (const float*)d_in[2];
    const float* c0_bl  = (const float*)d_in[3];
    const float* c0_wr  = (const float*)d_in[4];
    const float* c0_br  = (const float*)d_in[5];
    const float* c0_att = (const float*)d_in[6];
    const float* c0_bias= (const float*)d_in[7];
    const float* c1_wl  = (const float*)d_in[8];
    const float* c1_bl  = (const float*)d_in[9];
    const float* c1_wr  = (const float*)d_in[10];
    const float* c1_br  = (const float*)d_in[11];
    const float* c1_att = (const float*)d_in[12];
    const float* c1_bias= (const float*)d_in[13];
    const float* gn0_w  = (const float*)d_in[14];
    const float* gn0_b  = (const float*)d_in[15];
    const float* gn0_ms = (const float*)d_in[16];
    const float* gn1_w  = (const float*)d_in[17];
    const float* gn1_b  = (const float*)d_in[18];
    const float* gn1_ms = (const float*)d_in[19];
    const float* lin0_w = (const float*)d_in[20];
    const float* lin0_b = (const float*)d_in[21];
    const float* lin1_w = (const float*)d_in[22];
    const float* lin1_b = (const float*)d_in[23];
    const float* lin2_w = (const float*)d_in[24];
    const float* lin2_b = (const float*)d_in[25];

    const int n = in_sizes[0] / 128;   // 50000
    const int E = in_sizes[1] / 2;     // 800000
    const int* src = eidx;
    const int* dst = eidx + E;

    char* wsp = (char*)d_ws;
    size_t off = 0;
    auto alloc = [&](size_t bytes) -> void* {
        void* p = wsp + off;
        off = (off + bytes + 255) & ~(size_t)255;
        return p;
    };
    unsigned short* xbf  = (unsigned short*)alloc((size_t)n * 128 * 2);
    unsigned short* xlr  = (unsigned short*)alloc((size_t)n * 512 * 2);
    unsigned short* hbB  = (unsigned short*)alloc((size_t)n * 256 * 2);
    unsigned short* Wt0  = (unsigned short*)alloc((size_t)512 * 128 * 2);
    unsigned short* Wt1  = (unsigned short*)alloc((size_t)512 * 256 * 2);
    unsigned short* Lt0  = (unsigned short*)alloc((size_t)64 * 256 * 2);
    unsigned short* Lt1  = (unsigned short*)alloc((size_t)64 * 64 * 2);
    int*   esrc    = (int*)alloc((size_t)E * 4);
    int*   row_ptr = (int*)alloc((size_t)(n + 1) * 4);
    int*   cursor  = (int*)alloc((size_t)n * 4);
    int*   hist    = (int*)alloc((size_t)n * 4);
    int*   bsum    = (int*)alloc((size_t)256 * 4);
    float* s_sum   = (float*)alloc(256 * 4);
    float* s_sq    = (float*)alloc(256 * 4);
    float* s_a     = (float*)alloc(256 * 4);
    float* s_c     = (float*)alloc(256 * 4);

    // ---- fused prep ----
    const int nx4 = n * 128 / 4;
    const int prep_total = 512 + n + nx4 + 32768 * 2 + 65536 * 2 + 16384 + 4096;
    prep_all<<<(prep_total + 255) / 256, 256, 0, stream>>>(
        x, xbf, nx4, c0_wl, c0_wr, Wt0, c1_wl, c1_wr, Wt1,
        lin0_w, Lt0, lin1_w, Lt1, s_sum, hist, n);

    // ---- CSR by dst ----
    const int nblk = (n + 255) / 256;   // 196
    hist_kernel<<<(E + 255) / 256, 256, 0, stream>>>(dst, E, hist);
    blk_sum_kernel<<<nblk, 256, 0, stream>>>(hist, n, bsum);
    final_scan_kernel<<<nblk, 256, 0, stream>>>(hist, bsum, nblk, n, row_ptr, cursor);
    scatter_kernel<<<(E + 255) / 256, 256, 0, stream>>>(src, dst, E, cursor, esrc);

    const int mtc = (n + 127) / 128;    // 391 conv M-tiles
    const int mt  = (n + 255) / 256;    // 196 MLP M-tiles
    const int gagg = (n + 3) / 4;

    // ---- conv0 ----
    conv_gemm<128, false><<<mtc * 4, 256, 0, stream>>>(
        xbf, Wt0, c0_bl, c0_br, 256, nullptr, nullptr, xlr, n, 512, 4);
    gat_aggregate<<<gagg, 256, 0, stream>>>(xlr, c0_att, row_ptr, esrc, c0_bias, hbB, n);
    colstats_bf16<<<1024, 256, 0, stream>>>(hbB, n, s_sum, s_sq);
    norm_finalize<<<1, 256, 0, stream>>>(s_sum, s_sq, gn0_w, gn0_b, gn0_ms, s_a, s_c, 1.f / n);

    // ---- conv1 (gn0 fused) ----
    conv_gemm<256, true><<<mtc * 4, 256, 0, stream>>>(
        hbB, Wt1, c1_bl, c1_br, 256, s_a, s_c, xlr, n, 512, 4);
    gat_aggregate<<<gagg, 256, 0, stream>>>(xlr, c1_att, row_ptr, esrc, c1_bias, hbB, n);
    colstats_bf16<<<1024, 256, 0, stream>>>(hbB, n, s_sum, s_sq);
    norm_finalize<<<1, 256, 0, stream>>>(s_sum, s_sq, gn1_w, gn1_b, gn1_ms, s_a, s_c, 1.f / n);

    // ---- fused MLP (gn1 fused on lin0's A) ----
    mlp_fused<<<mt, 256, 0, stream>>>(
        hbB, Lt0, lin0_b, s_a, s_c, Lt1, lin1_b, lin2_w, lin2_b, (float*)d_out, n);
}